// Round 6
// baseline (412.740 us; speedup 1.0000x reference)
//
#include <hip/hip_runtime.h>
#include <hip/hip_fp16.h>

#define ND 25000
#define NG 20000
#define NTOT (ND + NG)      // 45000
#define NBLK 128            // hist/fill slices PER NODE TYPE
#define PREPB 1024          // prep blocks appended after the 256 hist blocks
#define NSB 176             // scan blocks: ceil(45000/256)
#define SFB 1024            // scanfill grid = NBLK*8 (all-resident: 4/CU, 25KB LDS -> 6/CU cap)
#define DRNG 6250           // disease nodes per XCD range (ND/4)
#define GRNG 5000           // gene nodes per XCD range (NG/4)
#define AGG_SLOTS 1563      // ceil(DRNG/4); agg grid = 8*AGG_SLOTS
#define AGG_GRID (8 * AGG_SLOTS)

typedef _Float16 half8 __attribute__((ext_vector_type(8)));
typedef float f32x4 __attribute__((ext_vector_type(4)));
typedef float f32x2 __attribute__((ext_vector_type(2)));

// ---- workspace layout (bytes), 256B-aligned ----
#define OFF_CNT    0ull           // NSB+1 u32: lookback flags + done-counter
#define OFF_ROW    180224ull      // NTOT+1 int
#define OFF_PARTD  360704ull      // NBLK*ND u16
#define OFF_PARTG  6760704ull     // NBLK*NG u16
#define OFF_COL    11880704ull    // 2*NE u16
#define OFF_WSW    15880704ull    // 8*128*128 half
#define OFF_XDH    16142848ull    // ND*128 half
#define OFF_XGH    22542848ull    // NG*128 half
#define OFF_X8D    27662848ull    // ND*128 fp8
#define OFF_X8G    30862848ull    // NG*128 fp8
#define OFF_MDH    33422848ull    // ND*128 half
#define OFF_MGH    39822848ull    // NG*128 half
#define OFF_D1H    44942848ull    // ND*128 half
#define OFF_G1H    51342848ull    // NG*128 half
#define OFF_D18    56462848ull    // ND*128 fp8
#define OFF_G18    59662848ull    // NG*128 fp8  (end ~62.2 MB)

struct WPtrs { const float* w[8]; };

// ---------------- dispatch 1: hist (blocks 0..2*NBLK-1) + prep/convert/swizzle (rest) ------------
__global__ __launch_bounds__(256) void prep_hist(const float* __restrict__ xd,
                                                 const float* __restrict__ xg,
                                                 __half* __restrict__ ydh,
                                                 __half* __restrict__ ygh,
                                                 unsigned char* __restrict__ y8d,
                                                 unsigned char* __restrict__ y8g,
                                                 WPtrs wp, _Float16* __restrict__ wsw,
                                                 const int* __restrict__ src,
                                                 const int* __restrict__ dst,
                                                 unsigned short* __restrict__ partD,
                                                 unsigned short* __restrict__ partG,
                                                 unsigned int* __restrict__ flags, int E) {
    __shared__ unsigned int h[12544];     // 50176 B
    int bx = blockIdx.x, t = threadIdx.x;
    if (bx < 2 * NBLK) {                  // ---- LDS-privatized histogram ----
        bool isD = bx < NBLK;
        int bb = isD ? bx : bx - NBLK;
        const int* key = isD ? src : dst;
        int nw = isD ? (ND / 2) : (NG / 2);
        for (int i = t; i < nw; i += 256) h[i] = 0;
        __syncthreads();
        int e0 = (int)(((long long)E * bb) / NBLK);
        int e1 = (int)(((long long)E * (bb + 1)) / NBLK);
        for (int e = e0 + t; e < e1; e += 256) {
            int k = key[e];
            atomicAdd(&h[k >> 1], 1u << ((k & 1) * 16));
        }
        __syncthreads();
        unsigned int* po = (unsigned int*)((isD ? partD : partG) + (size_t)bb * (isD ? ND : NG));
        for (int i = t; i < nw; i += 256) po[i] = h[i];
        return;
    }
    int pb = bx - 2 * NBLK;               // ---- prep: convert + swizzle ----
    if (pb < 8) {   // W swizzle: slot=(ntile*4+kc)*64+lane; elem j = W[kc*32+(lane>>4)*8+j][ntile*16+(lane&15)]
        const float* W = wp.w[pb];
        _Float16* o = wsw + (size_t)pb * 16384;
        for (int rep = 0; rep < 8; ++rep) {
            int slot = rep * 256 + t;
            int lane = slot & 63, grp = slot >> 6;
            int kc = grp & 3, ntile = grp >> 2;
            int nn = ntile * 16 + (lane & 15);
            int kb = kc * 32 + (lane >> 4) * 8;
            half8 v;
#pragma unroll
            for (int j = 0; j < 8; ++j) v[j] = (_Float16)W[(size_t)(kb + j) * 128 + nn];
            *(half8*)(o + (size_t)slot * 8) = v;
        }
    } else if (pb == 8 && t <= NSB) {     // zero lookback flags + done-counter
        flags[t] = 0u;
    }
    const int ndq = ND * 32;
    const int tot = ndq + NG * 32;
    for (int i = pb * 256 + t; i < tot; i += PREPB * 256) {
        const float* x;
        __half* y;
        unsigned char* y8;
        int idx;
        if (i < ndq) { x = xd; y = ydh; y8 = y8d; idx = i; }
        else         { x = xg; y = ygh; y8 = y8g; idx = i - ndq; }
        float4 v = ((const float4*)x)[idx];
        ((__half2*)y)[idx * 2 + 0] = __floats2half2_rn(v.x, v.y);
        ((__half2*)y)[idx * 2 + 1] = __floats2half2_rn(v.z, v.w);
        int p8 = __builtin_amdgcn_cvt_pk_fp8_f32(v.x, v.y, 0, false);
        p8 = __builtin_amdgcn_cvt_pk_fp8_f32(v.z, v.w, p8, true);
        ((int*)y8)[idx] = p8;
    }
}

// ---------------- dispatch 2: fused scan (lookback) + spin-barrier + XCD-local fill --------------
// Blocks 0..NSB-1 run the proven scanall body, then release-increment the done-counter
// (flags[NSB]); all SFB blocks spin until done==NSB (all resident: 1024 blocks = 4/CU at
// 25KB LDS <= 6/CU cap -- barrier mechanics validated in round 4's csrfin), then run the
// round-5 fill2x body (LDS cursors, XCD-range-local col writes). Saves one launch boundary.
__global__ __launch_bounds__(256) void scanfill(unsigned short* __restrict__ partD,
                                                unsigned short* __restrict__ partG,
                                                int* __restrict__ row,
                                                unsigned int* __restrict__ flags,
                                                const int* __restrict__ src,
                                                const int* __restrict__ dst,
                                                unsigned short* __restrict__ col, int E) {
    __shared__ unsigned int cur[DRNG];    // 25000 B; first 1KB aliased as scan scratch
    __shared__ int sbase;
    int t = threadIdx.x, bid = blockIdx.x;
    int* sd = (int*)cur;
    if (bid < NSB) {                      // ---- scan phase (round-5 scanall body) ----
        int k = bid * 256 + t;
        int run = 0;
        if (k < NTOT) {
            unsigned short* part;
            int nb, kk;
            if (k < ND) { part = partD; nb = ND; kk = k; }
            else        { part = partG; nb = NG; kk = k - ND; }
#pragma unroll 8
            for (int b = 0; b < NBLK; ++b) {
                size_t idx = (size_t)b * nb + kk;
                int v = part[idx];
                part[idx] = (unsigned short)run;
                run += v;
            }
        }
        int tsum = run;
        sd[t] = tsum;
        __syncthreads();
        for (int off = 1; off < 256; off <<= 1) {
            int x = (t >= off) ? sd[t - off] : 0;
            __syncthreads();
            sd[t] += x;
            __syncthreads();
        }
        if (t == 0)                       // publish block aggregate (+1 so 0 == not-ready)
            __hip_atomic_store(&flags[bid], (unsigned int)sd[255] + 1u,
                               __ATOMIC_RELEASE, __HIP_MEMORY_SCOPE_AGENT);
        if (t < 64) {                     // parallel lookback over predecessors
            int s = 0;
            for (int i = t; i < bid; i += 64) {
                unsigned int v;
                do {
                    v = __hip_atomic_load(&flags[i], __ATOMIC_ACQUIRE, __HIP_MEMORY_SCOPE_AGENT);
                } while (v == 0u);
                s += (int)v - 1;
            }
#pragma unroll
            for (int off = 1; off < 64; off <<= 1) s += __shfl_xor(s, off, 64);
            if (t == 0) sbase = s;
        }
        __syncthreads();
        if (k < NTOT) row[k] = sbase + sd[t] - tsum;
        if (bid == 0 && t == 0) row[NTOT] = 2 * E;
        __syncthreads();
        if (t == 0)                       // scan chunk done (release: row/part visible)
            __hip_atomic_fetch_add((int*)&flags[NSB], 1,
                                   __ATOMIC_RELEASE, __HIP_MEMORY_SCOPE_AGENT);
    }
    if (t == 0) {                         // ---- barrier: wait for all NSB scan chunks ----
        while (__hip_atomic_load((int*)&flags[NSB], __ATOMIC_ACQUIRE,
                                 __HIP_MEMORY_SCOPE_AGENT) < NSB)
            __builtin_amdgcn_s_sleep(2);
    }
    __syncthreads();
    // ---- fill phase (round-5 fill2x body) ----
    int x = bid & 7;                      // range / XCD id
    int s = bid >> 3;                     // edge slice 0..NBLK-1
    bool isD = x < 4;
    int r0, rng, nbase, nb;
    const int *key, *val;
    const unsigned short* part;
    if (isD) { r0 = x * DRNG;       rng = DRNG; key = src; val = dst; part = partD; nb = ND; nbase = 0;  }
    else     { r0 = (x - 4) * GRNG; rng = GRNG; key = dst; val = src; part = partG; nb = NG; nbase = ND; }
    for (int i = t; i < rng; i += 256)
        cur[i] = (unsigned int)row[nbase + r0 + i] + part[(size_t)s * nb + r0 + i];
    __syncthreads();
    int e0 = (int)(((long long)E * s) / NBLK);
    int e1 = (int)(((long long)E * (s + 1)) / NBLK);
    for (int e = e0 + t; e < e1; e += 256) {
        int k = key[e];
        if (k >= r0 && k < r0 + rng) {
            unsigned int p = atomicAdd(&cur[k - r0], 1u);
            col[p] = (unsigned short)val[e];
        }
    }
}

// ---------------- dispatches 3/5: fp8 mean aggregation, range-aligned XCD pinning ----------------
// 1 wave per node, 8 lanes x 16B per neighbor row, FOUR rows in flight per lane-group
// (4 independent col loads issued back-to-back, then 4 independent gathers -> 2x the
// memory-level parallelism of the previous 2-deep loop against the col->gather chain).
__global__ __launch_bounds__(256, 8) void agg8m(const unsigned char* __restrict__ Xg,
                                                const unsigned char* __restrict__ Xd,
                                                const int* __restrict__ row,
                                                const unsigned short* __restrict__ col,
                                                __half* __restrict__ outd,
                                                __half* __restrict__ outg) {
    int wid = threadIdx.x >> 6, lane = threadIdx.x & 63;
    int bid = blockIdx.x;
    int xcd = bid & 7, slot = bid >> 3;
    const unsigned char* X;
    _Float16* out;
    int node, nloc;
    if (xcd < 4) {                        // disease range on XCD xcd
        int loc = slot * 4 + wid;
        if (loc >= DRNG) return;
        nloc = xcd * DRNG + loc;
        if (nloc >= ND) return;
        node = nloc;
        X = Xg; out = (_Float16*)outd;
    } else {                              // gene range on XCD xcd
        int loc = slot * 4 + wid;
        if (loc >= GRNG) return;
        nloc = (xcd - 4) * GRNG + loc;
        if (nloc >= NG) return;
        node = ND + nloc;
        X = Xd; out = (_Float16*)outg;
    }
    int b = row[node], e = row[node + 1];
    int g = lane >> 3, f = lane & 7;
    float acc[16];
#pragma unroll
    for (int k = 0; k < 16; ++k) acc[k] = 0.f;
    int j = b + g;
    for (; j + 24 < e; j += 32) {         // 4-deep: all col loads, then all gathers
        int c0 = col[j], c1 = col[j + 8], c2 = col[j + 16], c3 = col[j + 24];
        int4 w0 = *(const int4*)(X + (size_t)c0 * 128 + f * 16);
        int4 w1 = *(const int4*)(X + (size_t)c1 * 128 + f * 16);
        int4 w2 = *(const int4*)(X + (size_t)c2 * 128 + f * 16);
        int4 w3 = *(const int4*)(X + (size_t)c3 * 128 + f * 16);
        const int* wa = (const int*)&w0;
        const int* wb = (const int*)&w1;
        const int* wc = (const int*)&w2;
        const int* wd = (const int*)&w3;
#pragma unroll
        for (int q = 0; q < 4; ++q) {
            f32x2 l0 = __builtin_amdgcn_cvt_pk_f32_fp8(wa[q], false);
            f32x2 h0 = __builtin_amdgcn_cvt_pk_f32_fp8(wa[q], true);
            f32x2 l1 = __builtin_amdgcn_cvt_pk_f32_fp8(wb[q], false);
            f32x2 h1 = __builtin_amdgcn_cvt_pk_f32_fp8(wb[q], true);
            f32x2 l2 = __builtin_amdgcn_cvt_pk_f32_fp8(wc[q], false);
            f32x2 h2 = __builtin_amdgcn_cvt_pk_f32_fp8(wc[q], true);
            f32x2 l3 = __builtin_amdgcn_cvt_pk_f32_fp8(wd[q], false);
            f32x2 h3 = __builtin_amdgcn_cvt_pk_f32_fp8(wd[q], true);
            acc[q * 4 + 0] += (l0[0] + l1[0]) + (l2[0] + l3[0]);
            acc[q * 4 + 1] += (l0[1] + l1[1]) + (l2[1] + l3[1]);
            acc[q * 4 + 2] += (h0[0] + h1[0]) + (h2[0] + h3[0]);
            acc[q * 4 + 3] += (h0[1] + h1[1]) + (h2[1] + h3[1]);
        }
    }
    for (; j < e; j += 8) {               // tail: up to 3 single neighbors
        int c = col[j];
        int4 w = *(const int4*)(X + (size_t)c * 128 + f * 16);
        const int* wa = (const int*)&w;
#pragma unroll
        for (int q = 0; q < 4; ++q) {
            f32x2 l = __builtin_amdgcn_cvt_pk_f32_fp8(wa[q], false);
            f32x2 h = __builtin_amdgcn_cvt_pk_f32_fp8(wa[q], true);
            acc[q * 4 + 0] += l[0];
            acc[q * 4 + 1] += l[1];
            acc[q * 4 + 2] += h[0];
            acc[q * 4 + 3] += h[1];
        }
    }
#pragma unroll
    for (int k = 0; k < 16; ++k) {
        acc[k] += __shfl_xor(acc[k], 8, 64);
        acc[k] += __shfl_xor(acc[k], 16, 64);
        acc[k] += __shfl_xor(acc[k], 32, 64);
    }
    if (g == 0) {
        int deg = e - b;
        float r = 1.0f / (float)(deg > 0 ? deg : 1);
        half8 o0, o1;
#pragma unroll
        for (int k = 0; k < 8; ++k) o0[k] = (_Float16)(acc[k] * r);
#pragma unroll
        for (int k = 0; k < 8; ++k) o1[k] = (_Float16)(acc[8 + k] * r);
        _Float16* op = out + (size_t)nloc * 128 + f * 16;
        *(half8*)op = o0;
        *(half8*)(op + 8) = o1;
    }
}

// ---------------- dispatches 4/6: merged MFMA dual GEMM ------------------------------------------
struct GemmDual {
    const __half *A1d, *A2d, *A1g, *A2g;
    const _Float16 *W1d, *W2d, *W1g, *W2g;
    const float *biasd, *biasg;
    float *Yfd, *Yfg;
    __half *Yhd, *Yhg;
    unsigned char *Y8d, *Y8g;
};
__global__ __launch_bounds__(256) void gemm2(GemmDual p, int nblkD, int layer) {
    int bx = blockIdx.x;
    bool isD = bx < nblkD;
    const __half* A1 = isD ? p.A1d : p.A1g;
    const __half* A2 = isD ? p.A2d : p.A2g;
    const _Float16* W1 = isD ? p.W1d : p.W1g;
    const _Float16* W2 = isD ? p.W2d : p.W2g;
    const float* bias = isD ? p.biasd : p.biasg;
    float* Yf = isD ? p.Yfd : p.Yfg;
    __half* Yh = isD ? p.Yhd : p.Yhg;
    unsigned char* Y8 = isD ? p.Y8d : p.Y8g;
    int n = isD ? ND : NG, b0 = isD ? bx : bx - nblkD;
    int t = threadIdx.x;
    int wave = t >> 6, lane = t & 63;
    int row0 = b0 * 64 + wave * 16;
    if (row0 >= n) return;
    int m = lane & 15, quad = lane >> 4;
    int arow = row0 + m;
    if (arow >= n) arow = n - 1;
    const _Float16* a1p = (const _Float16*)A1 + (size_t)arow * 128 + quad * 8;
    const _Float16* a2p = (const _Float16*)A2 + (size_t)arow * 128 + quad * 8;
    half8 a1[4], a2[4];
#pragma unroll
    for (int kc = 0; kc < 4; ++kc) {
        a1[kc] = *(const half8*)(a1p + kc * 32);
        a2[kc] = *(const half8*)(a2p + kc * 32);
    }
#pragma unroll
    for (int ntile = 0; ntile < 8; ++ntile) {
        f32x4 acc = {0.f, 0.f, 0.f, 0.f};
#pragma unroll
        for (int kc = 0; kc < 4; ++kc) {
            half8 b1 = *(const half8*)(W1 + (size_t)((ntile * 4 + kc) * 64 + lane) * 8);
            acc = __builtin_amdgcn_mfma_f32_16x16x32_f16(a1[kc], b1, acc, 0, 0, 0);
            half8 b2 = *(const half8*)(W2 + (size_t)((ntile * 4 + kc) * 64 + lane) * 8);
            acc = __builtin_amdgcn_mfma_f32_16x16x32_f16(a2[kc], b2, acc, 0, 0, 0);
        }
        int colx = ntile * 16 + m;
        float bb = bias[colx];
#pragma unroll
        for (int r = 0; r < 4; ++r) {
            int rr = row0 + quad * 4 + r;
            if (rr < n) {
                float v = acc[r] + bb;
                if (layer == 2) {
                    Yf[(size_t)rr * 128 + colx] = v;
                } else {
                    Yh[(size_t)rr * 128 + colx] = __float2half(v);
                    int p8 = __builtin_amdgcn_cvt_pk_fp8_f32(v, v, 0, false);
                    Y8[(size_t)rr * 128 + colx] = (unsigned char)(p8 & 0xff);
                }
            }
        }
    }
}

extern "C" void kernel_launch(void* const* d_in, const int* in_sizes, int n_in,
                              void* d_out, int out_size, void* d_ws, size_t ws_size,
                              hipStream_t stream) {
    const float* x_d = (const float*)d_in[0];
    const float* x_g = (const float*)d_in[1];
    const int*   src = (const int*)d_in[2];
    const int*   dst = (const int*)d_in[3];
    float* out = (float*)d_out;

    char* ws = (char*)d_ws;
    unsigned int*   flags = (unsigned int*)(ws + OFF_CNT);
    int*            row   = (int*)(ws + OFF_ROW);
    unsigned short* partD = (unsigned short*)(ws + OFF_PARTD);
    unsigned short* partG = (unsigned short*)(ws + OFF_PARTG);
    unsigned short* col   = (unsigned short*)(ws + OFF_COL);
    _Float16*       wsw   = (_Float16*)(ws + OFF_WSW);
    __half*         xd_h  = (__half*)(ws + OFF_XDH);
    __half*         xg_h  = (__half*)(ws + OFF_XGH);
    unsigned char*  x8d   = (unsigned char*)(ws + OFF_X8D);
    unsigned char*  x8g   = (unsigned char*)(ws + OFF_X8G);
    __half*         md_h  = (__half*)(ws + OFF_MDH);
    __half*         mg_h  = (__half*)(ws + OFF_MGH);
    __half*         d1_h  = (__half*)(ws + OFF_D1H);
    __half*         g1_h  = (__half*)(ws + OFF_G1H);
    unsigned char*  d1_8  = (unsigned char*)(ws + OFF_D18);
    unsigned char*  g1_8  = (unsigned char*)(ws + OFF_G18);

    const int E = in_sizes[2];              // 1,000,000
    const int nblkD = (ND + 63) / 64;       // 391
    const int nblkG = (NG + 63) / 64;       // 313

    WPtrs wp;
    wp.w[0] = (const float*)d_in[4];   // w1_dg_l
    wp.w[1] = (const float*)d_in[6];   // w1_dg_r
    wp.w[2] = (const float*)d_in[7];   // w1_gd_l
    wp.w[3] = (const float*)d_in[9];   // w1_gd_r
    wp.w[4] = (const float*)d_in[10];  // w2_dg_l
    wp.w[5] = (const float*)d_in[12];  // w2_dg_r
    wp.w[6] = (const float*)d_in[13];  // w2_gd_l
    wp.w[7] = (const float*)d_in[15];  // w2_gd_r
    const float* b1_dg = (const float*)d_in[5];
    const float* b1_gd = (const float*)d_in[8];
    const float* b2_dg = (const float*)d_in[11];
    const float* b2_gd = (const float*)d_in[14];

    // 1. hist + prep (independent, disjoint block ranges) + flag zeroing
    prep_hist<<<2 * NBLK + PREPB, 256, 0, stream>>>(x_d, x_g, xd_h, xg_h, x8d, x8g,
                                                    wp, wsw, src, dst, partD, partG, flags, E);
    // 2. fused scan -> rowptr -> spin-barrier -> XCD-local fill
    scanfill<<<SFB, 256, 0, stream>>>(partD, partG, row, flags, src, dst, col, E);

    // 3-4. layer 1
    agg8m<<<AGG_GRID, 256, 0, stream>>>(x8g, x8d, row, col, md_h, mg_h);
    GemmDual g1p;
    g1p.A1d = md_h; g1p.A2d = xd_h; g1p.W1d = wsw + 2 * 16384; g1p.W2d = wsw + 3 * 16384;
    g1p.biasd = b1_gd; g1p.Yfd = nullptr; g1p.Yhd = d1_h; g1p.Y8d = d1_8;
    g1p.A1g = mg_h; g1p.A2g = xg_h; g1p.W1g = wsw + 0 * 16384; g1p.W2g = wsw + 1 * 16384;
    g1p.biasg = b1_dg; g1p.Yfg = nullptr; g1p.Yhg = g1_h; g1p.Y8g = g1_8;
    gemm2<<<nblkD + nblkG, 256, 0, stream>>>(g1p, nblkD, 1);

    // 5-6. layer 2
    agg8m<<<AGG_GRID, 256, 0, stream>>>(g1_8, d1_8, row, col, md_h, mg_h);
    GemmDual g2p;
    g2p.A1d = md_h; g2p.A2d = d1_h; g2p.W1d = wsw + 6 * 16384; g2p.W2d = wsw + 7 * 16384;
    g2p.biasd = b2_gd; g2p.Yfd = out; g2p.Yhd = nullptr; g2p.Y8d = nullptr;
    g2p.A1g = mg_h; g2p.A2g = g1_h; g2p.W1g = wsw + 4 * 16384; g2p.W2g = wsw + 5 * 16384;
    g2p.biasg = b2_dg; g2p.Yfg = out + (size_t)ND * 128; g2p.Yhg = nullptr; g2p.Y8g = nullptr;
    gemm2<<<nblkD + nblkG, 256, 0, stream>>>(g2p, nblkD, 2);
}

// Round 7
// 292.325 us; speedup vs baseline: 1.4119x; 1.4119x over previous
//
#include <hip/hip_runtime.h>
#include <hip/hip_fp16.h>

#define ND 25000
#define NG 20000
#define NTOT (ND + NG)      // 45000
#define NBLK 128            // hist/fill slices PER NODE TYPE
#define PREPB 1024          // prep blocks appended after the 256 hist blocks
#define NSCB 704            // scan blocks: ceil(45000/64), 64 keys/block
#define DRNG 6250           // disease nodes per XCD range (ND/4)
#define GRNG 5000           // gene nodes per XCD range (NG/4)
#define AGG_SLOTS 1563      // ceil(DRNG/4); agg grid = 8*AGG_SLOTS
#define AGG_GRID (8 * AGG_SLOTS)

typedef _Float16 half8 __attribute__((ext_vector_type(8)));
typedef float f32x4 __attribute__((ext_vector_type(4)));
typedef float f32x2 __attribute__((ext_vector_type(2)));

// ---- workspace layout (bytes), 256B-aligned ----
#define OFF_CNT    0ull           // NSCB u32 lookback flags
#define OFF_ROW    180224ull      // NTOT+1 int
#define OFF_PARTD  360704ull      // NBLK*ND u16
#define OFF_PARTG  6760704ull     // NBLK*NG u16
#define OFF_COL    11880704ull    // 2*NE u16
#define OFF_WSW    15880704ull    // 8*128*128 half
#define OFF_XDH    16142848ull    // ND*128 half
#define OFF_XGH    22542848ull    // NG*128 half
#define OFF_X8D    27662848ull    // ND*128 fp8
#define OFF_X8G    30862848ull    // NG*128 fp8
#define OFF_MDH    33422848ull    // ND*128 half
#define OFF_MGH    39822848ull    // NG*128 half
#define OFF_D1H    44942848ull    // ND*128 half
#define OFF_G1H    51342848ull    // NG*128 half
#define OFF_D18    56462848ull    // ND*128 fp8
#define OFF_G18    59662848ull    // NG*128 fp8  (end ~62.2 MB)

struct WPtrs { const float* w[8]; };

// ---------------- dispatch 1: hist (blocks 0..2*NBLK-1) + prep/convert/swizzle (rest) ------------
__global__ __launch_bounds__(256) void prep_hist(const float* __restrict__ xd,
                                                 const float* __restrict__ xg,
                                                 __half* __restrict__ ydh,
                                                 __half* __restrict__ ygh,
                                                 unsigned char* __restrict__ y8d,
                                                 unsigned char* __restrict__ y8g,
                                                 WPtrs wp, _Float16* __restrict__ wsw,
                                                 const int* __restrict__ src,
                                                 const int* __restrict__ dst,
                                                 unsigned short* __restrict__ partD,
                                                 unsigned short* __restrict__ partG,
                                                 unsigned int* __restrict__ flags, int E) {
    __shared__ unsigned int h[12544];     // 50176 B
    int bx = blockIdx.x, t = threadIdx.x;
    if (bx < 2 * NBLK) {                  // ---- LDS-privatized histogram ----
        bool isD = bx < NBLK;
        int bb = isD ? bx : bx - NBLK;
        const int* key = isD ? src : dst;
        int nw = isD ? (ND / 2) : (NG / 2);
        for (int i = t; i < nw; i += 256) h[i] = 0;
        __syncthreads();
        int e0 = (int)(((long long)E * bb) / NBLK);
        int e1 = (int)(((long long)E * (bb + 1)) / NBLK);
        for (int e = e0 + t; e < e1; e += 256) {
            int k = key[e];
            atomicAdd(&h[k >> 1], 1u << ((k & 1) * 16));
        }
        __syncthreads();
        unsigned int* po = (unsigned int*)((isD ? partD : partG) + (size_t)bb * (isD ? ND : NG));
        for (int i = t; i < nw; i += 256) po[i] = h[i];
        return;
    }
    int pb = bx - 2 * NBLK;               // ---- prep: convert + swizzle ----
    if (pb < 8) {   // W swizzle: slot=(ntile*4+kc)*64+lane; elem j = W[kc*32+(lane>>4)*8+j][ntile*16+(lane&15)]
        const float* W = wp.w[pb];
        _Float16* o = wsw + (size_t)pb * 16384;
        for (int rep = 0; rep < 8; ++rep) {
            int slot = rep * 256 + t;
            int lane = slot & 63, grp = slot >> 6;
            int kc = grp & 3, ntile = grp >> 2;
            int nn = ntile * 16 + (lane & 15);
            int kb = kc * 32 + (lane >> 4) * 8;
            half8 v;
#pragma unroll
            for (int j = 0; j < 8; ++j) v[j] = (_Float16)W[(size_t)(kb + j) * 128 + nn];
            *(half8*)(o + (size_t)slot * 8) = v;
        }
    } else if (pb == 8) {                 // zero lookback flags for scanpar
        for (int i = t; i < NSCB; i += 256) flags[i] = 0u;
    }
    const int ndq = ND * 32;
    const int tot = ndq + NG * 32;
    for (int i = pb * 256 + t; i < tot; i += PREPB * 256) {
        const float* x;
        __half* y;
        unsigned char* y8;
        int idx;
        if (i < ndq) { x = xd; y = ydh; y8 = y8d; idx = i; }
        else         { x = xg; y = ygh; y8 = y8g; idx = i - ndq; }
        float4 v = ((const float4*)x)[idx];
        ((__half2*)y)[idx * 2 + 0] = __floats2half2_rn(v.x, v.y);
        ((__half2*)y)[idx * 2 + 1] = __floats2half2_rn(v.z, v.w);
        int p8 = __builtin_amdgcn_cvt_pk_fp8_f32(v.x, v.y, 0, false);
        p8 = __builtin_amdgcn_cvt_pk_fp8_f32(v.z, v.w, p8, true);
        ((int*)y8)[idx] = p8;
    }
}

// ---------------- dispatch 2: occupancy-parallel column scan + row-ptr (lookback) ----------------
// 4 threads per key x 32 slices, 64 keys/block -> 704 blocks (2.75/CU vs old 0.69/CU).
// Two-pass per thread: pass1 sums its 32 slices (streaming, independent loads); LDS combine +
// 64-lane shfl prefix over the block's keys + proven lookback over NSCB flags; pass2 re-walks
// the 32 slices (L2-hot) writing the LOCAL per-key prefix (u16-safe; fill adds row[] base).
__global__ __launch_bounds__(256) void scanpar(unsigned short* __restrict__ partD,
                                               unsigned short* __restrict__ partG,
                                               int* __restrict__ row,
                                               unsigned int* __restrict__ flags, int E) {
    __shared__ int ssum[4][64];
    __shared__ int stot[64];
    __shared__ int sprefix[64];
    __shared__ int sbase;
    int t = threadIdx.x, bid = blockIdx.x;
    int p = t >> 6, kl = t & 63;          // part 0..3, key-lane 0..63
    int k = bid * 64 + kl;
    unsigned short* part = partD;
    int nb = ND, kk = k;
    bool valid = (k < NTOT);
    if (valid && k >= ND) { part = partG; nb = NG; kk = k - ND; }
    // ---- pass 1: per-thread sum of its 32 slices ----
    int sum = 0;
    if (valid) {
#pragma unroll
        for (int b = 0; b < 32; ++b)
            sum += part[(size_t)(p * 32 + b) * nb + kk];
    }
    ssum[p][kl] = sum;
    __syncthreads();
    int pbase = 0;                        // intra-key offset of this thread's slice range
    for (int q = 0; q < p; ++q) pbase += ssum[q][kl];
    if (p == 0) stot[kl] = ssum[0][kl] + ssum[1][kl] + ssum[2][kl] + ssum[3][kl];
    __syncthreads();
    if (t < 64) {                         // wave 0: block prefix + publish + lookback
        int v = stot[t];
        for (int off = 1; off < 64; off <<= 1) {
            int u = __shfl_up(v, off, 64);
            if (t >= off) v += u;
        }
        sprefix[t] = v - stot[t];         // exclusive prefix within block
        if (t == 63)                      // publish block aggregate (+1 so 0 == not-ready)
            __hip_atomic_store(&flags[bid], (unsigned int)v + 1u,
                               __ATOMIC_RELEASE, __HIP_MEMORY_SCOPE_AGENT);
        int s = 0;                        // parallel lookback over predecessors
        for (int i = t; i < bid; i += 64) {
            unsigned int vv;
            do {
                vv = __hip_atomic_load(&flags[i], __ATOMIC_ACQUIRE, __HIP_MEMORY_SCOPE_AGENT);
            } while (vv == 0u);
            s += (int)vv - 1;
        }
#pragma unroll
        for (int off = 1; off < 64; off <<= 1) s += __shfl_xor(s, off, 64);
        if (t == 0) sbase = s;
    }
    __syncthreads();
    if (valid && p == 0) row[k] = sbase + sprefix[kl];
    if (bid == 0 && t == 0) row[NTOT] = 2 * E;
    // ---- pass 2: rewrite partials as LOCAL per-key running prefix ----
    if (valid) {
        int run = pbase;
        for (int b = 0; b < 32; ++b) {
            size_t idx = (size_t)(p * 32 + b) * nb + kk;
            int v = part[idx];
            part[idx] = (unsigned short)run;
            run += v;
        }
    }
}

// ---------------- dispatch 3: XCD-write-local CSR fill -------------------------------------------
__global__ __launch_bounds__(256) void fill2x(const int* __restrict__ src,
                                              const int* __restrict__ dst,
                                              const int* __restrict__ row,
                                              const unsigned short* __restrict__ partD,
                                              const unsigned short* __restrict__ partG,
                                              unsigned short* __restrict__ col, int E) {
    __shared__ unsigned int cur[DRNG];    // 25000 B (max of DRNG, GRNG)
    int t = threadIdx.x, bid = blockIdx.x;
    int x = bid & 7;                      // range / XCD id
    int s = bid >> 3;                     // edge slice 0..NBLK-1
    bool isD = x < 4;
    int r0, rng, nbase, nb;
    const int *key, *val;
    const unsigned short* part;
    if (isD) { r0 = x * DRNG;       rng = DRNG; key = src; val = dst; part = partD; nb = ND; nbase = 0;  }
    else     { r0 = (x - 4) * GRNG; rng = GRNG; key = dst; val = src; part = partG; nb = NG; nbase = ND; }
    for (int i = t; i < rng; i += 256)
        cur[i] = (unsigned int)row[nbase + r0 + i] + part[(size_t)s * nb + r0 + i];
    __syncthreads();
    int e0 = (int)(((long long)E * s) / NBLK);
    int e1 = (int)(((long long)E * (s + 1)) / NBLK);
    for (int e = e0 + t; e < e1; e += 256) {
        int k = key[e];
        if (k >= r0 && k < r0 + rng) {
            unsigned int p = atomicAdd(&cur[k - r0], 1u);
            col[p] = (unsigned short)val[e];
        }
    }
}

// ---------------- dispatches 4/6: fp8 mean aggregation, range-aligned XCD pinning ----------------
// 1 wave per node, 8 lanes x 16B per neighbor row, 4 rows in flight per lane-group.
__global__ __launch_bounds__(256, 8) void agg8m(const unsigned char* __restrict__ Xg,
                                                const unsigned char* __restrict__ Xd,
                                                const int* __restrict__ row,
                                                const unsigned short* __restrict__ col,
                                                __half* __restrict__ outd,
                                                __half* __restrict__ outg) {
    int wid = threadIdx.x >> 6, lane = threadIdx.x & 63;
    int bid = blockIdx.x;
    int xcd = bid & 7, slot = bid >> 3;
    const unsigned char* X;
    _Float16* out;
    int node, nloc;
    if (xcd < 4) {                        // disease range on XCD xcd
        int loc = slot * 4 + wid;
        if (loc >= DRNG) return;
        nloc = xcd * DRNG + loc;
        if (nloc >= ND) return;
        node = nloc;
        X = Xg; out = (_Float16*)outd;
    } else {                              // gene range on XCD xcd
        int loc = slot * 4 + wid;
        if (loc >= GRNG) return;
        nloc = (xcd - 4) * GRNG + loc;
        if (nloc >= NG) return;
        node = ND + nloc;
        X = Xd; out = (_Float16*)outg;
    }
    int b = row[node], e = row[node + 1];
    int g = lane >> 3, f = lane & 7;
    float acc[16];
#pragma unroll
    for (int k = 0; k < 16; ++k) acc[k] = 0.f;
    int j = b + g;
    for (; j + 24 < e; j += 32) {         // 4-deep: all col loads, then all gathers
        int c0 = col[j], c1 = col[j + 8], c2 = col[j + 16], c3 = col[j + 24];
        int4 w0 = *(const int4*)(X + (size_t)c0 * 128 + f * 16);
        int4 w1 = *(const int4*)(X + (size_t)c1 * 128 + f * 16);
        int4 w2 = *(const int4*)(X + (size_t)c2 * 128 + f * 16);
        int4 w3 = *(const int4*)(X + (size_t)c3 * 128 + f * 16);
        const int* wa = (const int*)&w0;
        const int* wb = (const int*)&w1;
        const int* wc = (const int*)&w2;
        const int* wd = (const int*)&w3;
#pragma unroll
        for (int q = 0; q < 4; ++q) {
            f32x2 l0 = __builtin_amdgcn_cvt_pk_f32_fp8(wa[q], false);
            f32x2 h0 = __builtin_amdgcn_cvt_pk_f32_fp8(wa[q], true);
            f32x2 l1 = __builtin_amdgcn_cvt_pk_f32_fp8(wb[q], false);
            f32x2 h1 = __builtin_amdgcn_cvt_pk_f32_fp8(wb[q], true);
            f32x2 l2 = __builtin_amdgcn_cvt_pk_f32_fp8(wc[q], false);
            f32x2 h2 = __builtin_amdgcn_cvt_pk_f32_fp8(wc[q], true);
            f32x2 l3 = __builtin_amdgcn_cvt_pk_f32_fp8(wd[q], false);
            f32x2 h3 = __builtin_amdgcn_cvt_pk_f32_fp8(wd[q], true);
            acc[q * 4 + 0] += (l0[0] + l1[0]) + (l2[0] + l3[0]);
            acc[q * 4 + 1] += (l0[1] + l1[1]) + (l2[1] + l3[1]);
            acc[q * 4 + 2] += (h0[0] + h1[0]) + (h2[0] + h3[0]);
            acc[q * 4 + 3] += (h0[1] + h1[1]) + (h2[1] + h3[1]);
        }
    }
    for (; j < e; j += 8) {               // tail
        int c = col[j];
        int4 w = *(const int4*)(X + (size_t)c * 128 + f * 16);
        const int* wa = (const int*)&w;
#pragma unroll
        for (int q = 0; q < 4; ++q) {
            f32x2 l = __builtin_amdgcn_cvt_pk_f32_fp8(wa[q], false);
            f32x2 h = __builtin_amdgcn_cvt_pk_f32_fp8(wa[q], true);
            acc[q * 4 + 0] += l[0];
            acc[q * 4 + 1] += l[1];
            acc[q * 4 + 2] += h[0];
            acc[q * 4 + 3] += h[1];
        }
    }
#pragma unroll
    for (int k = 0; k < 16; ++k) {
        acc[k] += __shfl_xor(acc[k], 8, 64);
        acc[k] += __shfl_xor(acc[k], 16, 64);
        acc[k] += __shfl_xor(acc[k], 32, 64);
    }
    if (g == 0) {
        int deg = e - b;
        float r = 1.0f / (float)(deg > 0 ? deg : 1);
        half8 o0, o1;
#pragma unroll
        for (int k = 0; k < 8; ++k) o0[k] = (_Float16)(acc[k] * r);
#pragma unroll
        for (int k = 0; k < 8; ++k) o1[k] = (_Float16)(acc[8 + k] * r);
        _Float16* op = out + (size_t)nloc * 128 + f * 16;
        *(half8*)op = o0;
        *(half8*)(op + 8) = o1;
    }
}

// ---------------- dispatches 5/7: merged MFMA dual GEMM ------------------------------------------
struct GemmDual {
    const __half *A1d, *A2d, *A1g, *A2g;
    const _Float16 *W1d, *W2d, *W1g, *W2g;
    const float *biasd, *biasg;
    float *Yfd, *Yfg;
    __half *Yhd, *Yhg;
    unsigned char *Y8d, *Y8g;
};
__global__ __launch_bounds__(256) void gemm2(GemmDual p, int nblkD, int layer) {
    int bx = blockIdx.x;
    bool isD = bx < nblkD;
    const __half* A1 = isD ? p.A1d : p.A1g;
    const __half* A2 = isD ? p.A2d : p.A2g;
    const _Float16* W1 = isD ? p.W1d : p.W1g;
    const _Float16* W2 = isD ? p.W2d : p.W2g;
    const float* bias = isD ? p.biasd : p.biasg;
    float* Yf = isD ? p.Yfd : p.Yfg;
    __half* Yh = isD ? p.Yhd : p.Yhg;
    unsigned char* Y8 = isD ? p.Y8d : p.Y8g;
    int n = isD ? ND : NG, b0 = isD ? bx : bx - nblkD;
    int t = threadIdx.x;
    int wave = t >> 6, lane = t & 63;
    int row0 = b0 * 64 + wave * 16;
    if (row0 >= n) return;
    int m = lane & 15, quad = lane >> 4;
    int arow = row0 + m;
    if (arow >= n) arow = n - 1;
    const _Float16* a1p = (const _Float16*)A1 + (size_t)arow * 128 + quad * 8;
    const _Float16* a2p = (const _Float16*)A2 + (size_t)arow * 128 + quad * 8;
    half8 a1[4], a2[4];
#pragma unroll
    for (int kc = 0; kc < 4; ++kc) {
        a1[kc] = *(const half8*)(a1p + kc * 32);
        a2[kc] = *(const half8*)(a2p + kc * 32);
    }
#pragma unroll
    for (int ntile = 0; ntile < 8; ++ntile) {
        f32x4 acc = {0.f, 0.f, 0.f, 0.f};
#pragma unroll
        for (int kc = 0; kc < 4; ++kc) {
            half8 b1 = *(const half8*)(W1 + (size_t)((ntile * 4 + kc) * 64 + lane) * 8);
            acc = __builtin_amdgcn_mfma_f32_16x16x32_f16(a1[kc], b1, acc, 0, 0, 0);
            half8 b2 = *(const half8*)(W2 + (size_t)((ntile * 4 + kc) * 64 + lane) * 8);
            acc = __builtin_amdgcn_mfma_f32_16x16x32_f16(a2[kc], b2, acc, 0, 0, 0);
        }
        int colx = ntile * 16 + m;
        float bb = bias[colx];
#pragma unroll
        for (int r = 0; r < 4; ++r) {
            int rr = row0 + quad * 4 + r;
            if (rr < n) {
                float v = acc[r] + bb;
                if (layer == 2) {
                    Yf[(size_t)rr * 128 + colx] = v;
                } else {
                    Yh[(size_t)rr * 128 + colx] = __float2half(v);
                    int p8 = __builtin_amdgcn_cvt_pk_fp8_f32(v, v, 0, false);
                    Y8[(size_t)rr * 128 + colx] = (unsigned char)(p8 & 0xff);
                }
            }
        }
    }
}

extern "C" void kernel_launch(void* const* d_in, const int* in_sizes, int n_in,
                              void* d_out, int out_size, void* d_ws, size_t ws_size,
                              hipStream_t stream) {
    const float* x_d = (const float*)d_in[0];
    const float* x_g = (const float*)d_in[1];
    const int*   src = (const int*)d_in[2];
    const int*   dst = (const int*)d_in[3];
    float* out = (float*)d_out;

    char* ws = (char*)d_ws;
    unsigned int*   flags = (unsigned int*)(ws + OFF_CNT);
    int*            row   = (int*)(ws + OFF_ROW);
    unsigned short* partD = (unsigned short*)(ws + OFF_PARTD);
    unsigned short* partG = (unsigned short*)(ws + OFF_PARTG);
    unsigned short* col   = (unsigned short*)(ws + OFF_COL);
    _Float16*       wsw   = (_Float16*)(ws + OFF_WSW);
    __half*         xd_h  = (__half*)(ws + OFF_XDH);
    __half*         xg_h  = (__half*)(ws + OFF_XGH);
    unsigned char*  x8d   = (unsigned char*)(ws + OFF_X8D);
    unsigned char*  x8g   = (unsigned char*)(ws + OFF_X8G);
    __half*         md_h  = (__half*)(ws + OFF_MDH);
    __half*         mg_h  = (__half*)(ws + OFF_MGH);
    __half*         d1_h  = (__half*)(ws + OFF_D1H);
    __half*         g1_h  = (__half*)(ws + OFF_G1H);
    unsigned char*  d1_8  = (unsigned char*)(ws + OFF_D18);
    unsigned char*  g1_8  = (unsigned char*)(ws + OFF_G18);

    const int E = in_sizes[2];              // 1,000,000
    const int nblkD = (ND + 63) / 64;       // 391
    const int nblkG = (NG + 63) / 64;       // 313

    WPtrs wp;
    wp.w[0] = (const float*)d_in[4];   // w1_dg_l
    wp.w[1] = (const float*)d_in[6];   // w1_dg_r
    wp.w[2] = (const float*)d_in[7];   // w1_gd_l
    wp.w[3] = (const float*)d_in[9];   // w1_gd_r
    wp.w[4] = (const float*)d_in[10];  // w2_dg_l
    wp.w[5] = (const float*)d_in[12];  // w2_dg_r
    wp.w[6] = (const float*)d_in[13];  // w2_gd_l
    wp.w[7] = (const float*)d_in[15];  // w2_gd_r
    const float* b1_dg = (const float*)d_in[5];
    const float* b1_gd = (const float*)d_in[8];
    const float* b2_dg = (const float*)d_in[11];
    const float* b2_gd = (const float*)d_in[14];

    // 1. hist + prep (independent, disjoint block ranges) + flag zeroing
    prep_hist<<<2 * NBLK + PREPB, 256, 0, stream>>>(x_d, x_g, xd_h, xg_h, x8d, x8g,
                                                    wp, wsw, src, dst, partD, partG, flags, E);
    // 2. occupancy-parallel scan -> rowptr (decoupled lookback)
    scanpar<<<NSCB, 256, 0, stream>>>(partD, partG, row, flags, E);
    // 3. XCD-write-local CSR fill
    fill2x<<<NBLK * 8, 256, 0, stream>>>(src, dst, row, partD, partG, col, E);

    // 4-5. layer 1
    agg8m<<<AGG_GRID, 256, 0, stream>>>(x8g, x8d, row, col, md_h, mg_h);
    GemmDual g1p;
    g1p.A1d = md_h; g1p.A2d = xd_h; g1p.W1d = wsw + 2 * 16384; g1p.W2d = wsw + 3 * 16384;
    g1p.biasd = b1_gd; g1p.Yfd = nullptr; g1p.Yhd = d1_h; g1p.Y8d = d1_8;
    g1p.A1g = mg_h; g1p.A2g = xg_h; g1p.W1g = wsw + 0 * 16384; g1p.W2g = wsw + 1 * 16384;
    g1p.biasg = b1_dg; g1p.Yfg = nullptr; g1p.Yhg = g1_h; g1p.Y8g = g1_8;
    gemm2<<<nblkD + nblkG, 256, 0, stream>>>(g1p, nblkD, 1);

    // 6-7. layer 2
    agg8m<<<AGG_GRID, 256, 0, stream>>>(g1_8, d1_8, row, col, md_h, mg_h);
    GemmDual g2p;
    g2p.A1d = md_h; g2p.A2d = d1_h; g2p.W1d = wsw + 6 * 16384; g2p.W2d = wsw + 7 * 16384;
    g2p.biasd = b2_gd; g2p.Yfd = out; g2p.Yhd = nullptr; g2p.Y8d = nullptr;
    g2p.A1g = mg_h; g2p.A2g = g1_h; g2p.W1g = wsw + 4 * 16384; g2p.W2g = wsw + 5 * 16384;
    g2p.biasg = b2_dg; g2p.Yfg = out + (size_t)ND * 128; g2p.Yhg = nullptr; g2p.Y8g = nullptr;
    gemm2<<<nblkD + nblkG, 256, 0, stream>>>(g2p, nblkD, 2);
}

// Round 8
// 275.896 us; speedup vs baseline: 1.4960x; 1.0596x over previous
//
#include <hip/hip_runtime.h>
#include <hip/hip_fp16.h>

#define ND 25000
#define NG 20000
#define NTOT (ND + NG)      // 45000
#define NBLK 64             // hist/fill slices PER NODE TYPE (halved: scan traffic/iters halve)
#define PREPB 1024          // prep blocks appended after the 2*NBLK hist blocks
#define NSB 176             // scan blocks: ceil(45000/256)
#define DRNG 6250           // disease nodes per XCD range (ND/4)
#define GRNG 5000           // gene nodes per XCD range (NG/4)
#define AGGB 2048           // agg grid: 8 blocks/CU, ALL resident -> exact bid&7->XCD pinning

typedef _Float16 half8 __attribute__((ext_vector_type(8)));
typedef float f32x4 __attribute__((ext_vector_type(4)));
typedef float f32x2 __attribute__((ext_vector_type(2)));

// ---- workspace layout (bytes), 256B-aligned ----
#define OFF_CNT    0ull           // NSB u32 lookback flags
#define OFF_ROW    180224ull      // NTOT+1 int
#define OFF_PARTD  360704ull      // NBLK*ND u16 (3,200,000)
#define OFF_PARTG  6760704ull     // NBLK*NG u16 (2,560,000)
#define OFF_COL    11880704ull    // 2*NE u16
#define OFF_WSW    15880704ull    // 8*128*128 half
#define OFF_XDH    16142848ull    // ND*128 half
#define OFF_XGH    22542848ull    // NG*128 half
#define OFF_X8D    27662848ull    // ND*128 fp8
#define OFF_X8G    30862848ull    // NG*128 fp8
#define OFF_MDH    33422848ull    // ND*128 half
#define OFF_MGH    39822848ull    // NG*128 half
#define OFF_D1H    44942848ull    // ND*128 half
#define OFF_G1H    51342848ull    // NG*128 half
#define OFF_D18    56462848ull    // ND*128 fp8
#define OFF_G18    59662848ull    // NG*128 fp8  (end ~62.2 MB)

struct WPtrs { const float* w[8]; };

// ---------------- dispatch 1: hist (blocks 0..2*NBLK-1) + prep/convert/swizzle (rest) ------------
__global__ __launch_bounds__(256) void prep_hist(const float* __restrict__ xd,
                                                 const float* __restrict__ xg,
                                                 __half* __restrict__ ydh,
                                                 __half* __restrict__ ygh,
                                                 unsigned char* __restrict__ y8d,
                                                 unsigned char* __restrict__ y8g,
                                                 WPtrs wp, _Float16* __restrict__ wsw,
                                                 const int* __restrict__ src,
                                                 const int* __restrict__ dst,
                                                 unsigned short* __restrict__ partD,
                                                 unsigned short* __restrict__ partG,
                                                 unsigned int* __restrict__ flags, int E) {
    __shared__ unsigned int h[12544];     // 50176 B
    int bx = blockIdx.x, t = threadIdx.x;
    if (bx < 2 * NBLK) {                  // ---- LDS-privatized histogram ----
        bool isD = bx < NBLK;
        int bb = isD ? bx : bx - NBLK;
        const int* key = isD ? src : dst;
        int nw = isD ? (ND / 2) : (NG / 2);
        for (int i = t; i < nw; i += 256) h[i] = 0;
        __syncthreads();
        int e0 = (int)(((long long)E * bb) / NBLK);
        int e1 = (int)(((long long)E * (bb + 1)) / NBLK);
        for (int e = e0 + t; e < e1; e += 256) {
            int k = key[e];
            atomicAdd(&h[k >> 1], 1u << ((k & 1) * 16));
        }
        __syncthreads();
        unsigned int* po = (unsigned int*)((isD ? partD : partG) + (size_t)bb * (isD ? ND : NG));
        for (int i = t; i < nw; i += 256) po[i] = h[i];
        return;
    }
    int pb = bx - 2 * NBLK;               // ---- prep: convert + swizzle ----
    if (pb < 8) {   // W swizzle: slot=(ntile*4+kc)*64+lane; elem j = W[kc*32+(lane>>4)*8+j][ntile*16+(lane&15)]
        const float* W = wp.w[pb];
        _Float16* o = wsw + (size_t)pb * 16384;
        for (int rep = 0; rep < 8; ++rep) {
            int slot = rep * 256 + t;
            int lane = slot & 63, grp = slot >> 6;
            int kc = grp & 3, ntile = grp >> 2;
            int nn = ntile * 16 + (lane & 15);
            int kb = kc * 32 + (lane >> 4) * 8;
            half8 v;
#pragma unroll
            for (int j = 0; j < 8; ++j) v[j] = (_Float16)W[(size_t)(kb + j) * 128 + nn];
            *(half8*)(o + (size_t)slot * 8) = v;
        }
    } else if (pb == 8 && t < NSB) {      // zero lookback flags for scanall
        flags[t] = 0u;
    }
    const int ndq = ND * 32;
    const int tot = ndq + NG * 32;
    for (int i = pb * 256 + t; i < tot; i += PREPB * 256) {
        const float* x;
        __half* y;
        unsigned char* y8;
        int idx;
        if (i < ndq) { x = xd; y = ydh; y8 = y8d; idx = i; }
        else         { x = xg; y = ygh; y8 = y8g; idx = i - ndq; }
        float4 v = ((const float4*)x)[idx];
        ((__half2*)y)[idx * 2 + 0] = __floats2half2_rn(v.x, v.y);
        ((__half2*)y)[idx * 2 + 1] = __floats2half2_rn(v.z, v.w);
        int p8 = __builtin_amdgcn_cvt_pk_fp8_f32(v.x, v.y, 0, false);
        p8 = __builtin_amdgcn_cvt_pk_fp8_f32(v.z, v.w, p8, true);
        ((int*)y8)[idx] = p8;
    }
}

// ---------------- dispatch 2: fused column-scan + row-ptr scan (decoupled lookback) --------------
// NBLK=64: per-key loop and partial traffic halved vs the 253us baseline.
__global__ __launch_bounds__(256) void scanall(unsigned short* __restrict__ partD,
                                               unsigned short* __restrict__ partG,
                                               int* __restrict__ row,
                                               unsigned int* __restrict__ flags, int E) {
    __shared__ int sd[256];
    __shared__ int sbase;
    int t = threadIdx.x, bid = blockIdx.x;
    int k = bid * 256 + t;
    int run = 0;
    if (k < NTOT) {                       // per-key scan over NBLK partial slices
        unsigned short* part;
        int nb, kk;
        if (k < ND) { part = partD; nb = ND; kk = k; }
        else        { part = partG; nb = NG; kk = k - ND; }
#pragma unroll 8
        for (int b = 0; b < NBLK; ++b) {
            size_t idx = (size_t)b * nb + kk;
            int v = part[idx];
            part[idx] = (unsigned short)run;
            run += v;
        }
    }
    int tsum = run;                       // this key's total degree
    sd[t] = tsum;
    __syncthreads();
    for (int off = 1; off < 256; off <<= 1) {   // block inclusive scan
        int x = (t >= off) ? sd[t - off] : 0;
        __syncthreads();
        sd[t] += x;
        __syncthreads();
    }
    if (t == 0) {                         // publish block aggregate (+1 so 0 == not-ready)
        unsigned int agg = (unsigned int)sd[255] + 1u;
        __hip_atomic_store(&flags[bid], agg, __ATOMIC_RELEASE, __HIP_MEMORY_SCOPE_AGENT);
    }
    if (t < 64) {                         // parallel lookback: sum ALL predecessor aggregates
        int s = 0;
        for (int i = t; i < bid; i += 64) {
            unsigned int v;
            do {
                v = __hip_atomic_load(&flags[i], __ATOMIC_ACQUIRE, __HIP_MEMORY_SCOPE_AGENT);
            } while (v == 0u);
            s += (int)v - 1;
        }
#pragma unroll
        for (int off = 1; off < 64; off <<= 1) s += __shfl_xor(s, off, 64);
        if (t == 0) sbase = s;
    }
    __syncthreads();
    int base = sbase;
    if (k < NTOT) row[k] = base + sd[t] - tsum;   // global exclusive prefix
    if (bid == 0 && t == 0) row[NTOT] = 2 * E;    // total is static
}

// ---------------- dispatch 3: XCD-write-local CSR fill (NBLK=64 -> 512 blocks) -------------------
__global__ __launch_bounds__(256) void fill2x(const int* __restrict__ src,
                                              const int* __restrict__ dst,
                                              const int* __restrict__ row,
                                              const unsigned short* __restrict__ partD,
                                              const unsigned short* __restrict__ partG,
                                              unsigned short* __restrict__ col, int E) {
    __shared__ unsigned int cur[DRNG];    // 25000 B (max of DRNG, GRNG)
    int t = threadIdx.x, bid = blockIdx.x;
    int x = bid & 7;                      // range / XCD id
    int s = bid >> 3;                     // edge slice 0..NBLK-1
    bool isD = x < 4;
    int r0, rng, nbase, nb;
    const int *key, *val;
    const unsigned short* part;
    if (isD) { r0 = x * DRNG;       rng = DRNG; key = src; val = dst; part = partD; nb = ND; nbase = 0;  }
    else     { r0 = (x - 4) * GRNG; rng = GRNG; key = dst; val = src; part = partG; nb = NG; nbase = ND; }
    for (int i = t; i < rng; i += 256)
        cur[i] = (unsigned int)row[nbase + r0 + i] + part[(size_t)s * nb + r0 + i];
    __syncthreads();
    int e0 = (int)(((long long)E * s) / NBLK);
    int e1 = (int)(((long long)E * (s + 1)) / NBLK);
    for (int e = e0 + t; e < e1; e += 256) {
        int k = key[e];
        if (k >= r0 && k < r0 + rng) {
            unsigned int p = atomicAdd(&cur[k - r0], 1u);
            col[p] = (unsigned short)val[e];
        }
    }
}

// ---------------- dispatches 4/6: fp8 mean aggregation, EXACT-resident XCD pinning ---------------
// Grid = 2048 blocks (8/CU, all co-resident at launch) -> bid&7 -> XCD mapping holds for the
// WHOLE dispatch (the old 12504-block grid only round-robins the first ~2048 blocks; later
// blocks drift and mix both gather tables in every L2). Each wave grid-strides its XCD's node
// range (stride 1024 waves/XCD); 4 neighbor rows in flight per lane-group.
__global__ __launch_bounds__(256, 8) void agg8m(const unsigned char* __restrict__ Xg,
                                                const unsigned char* __restrict__ Xd,
                                                const int* __restrict__ row,
                                                const unsigned short* __restrict__ col,
                                                __half* __restrict__ outd,
                                                __half* __restrict__ outg) {
    int wid = threadIdx.x >> 6, lane = threadIdx.x & 63;
    int bid = blockIdx.x;
    int xcd = bid & 7;
    int ws = (bid >> 3) * 4 + wid;        // wave slot 0..1023 within this XCD
    const unsigned char* X;
    _Float16* out;
    int base, rng, nodeoff;
    if (xcd < 4) { X = Xg; out = (_Float16*)outd; base = xcd * DRNG;       rng = DRNG; nodeoff = 0;  }
    else         { X = Xd; out = (_Float16*)outg; base = (xcd - 4) * GRNG; rng = GRNG; nodeoff = ND; }
    int g = lane >> 3, f = lane & 7;
    for (int loc = ws; loc < rng; loc += 1024) {
        int nloc = base + loc;
        int node = nodeoff + nloc;
        int b = row[node], e = row[node + 1];
        float acc[16];
#pragma unroll
        for (int k = 0; k < 16; ++k) acc[k] = 0.f;
        int j = b + g;
        for (; j + 24 < e; j += 32) {     // 4-deep: all col loads, then all gathers
            int c0 = col[j], c1 = col[j + 8], c2 = col[j + 16], c3 = col[j + 24];
            int4 w0 = *(const int4*)(X + (size_t)c0 * 128 + f * 16);
            int4 w1 = *(const int4*)(X + (size_t)c1 * 128 + f * 16);
            int4 w2 = *(const int4*)(X + (size_t)c2 * 128 + f * 16);
            int4 w3 = *(const int4*)(X + (size_t)c3 * 128 + f * 16);
            const int* wa = (const int*)&w0;
            const int* wb = (const int*)&w1;
            const int* wc = (const int*)&w2;
            const int* wd = (const int*)&w3;
#pragma unroll
            for (int q = 0; q < 4; ++q) {
                f32x2 l0 = __builtin_amdgcn_cvt_pk_f32_fp8(wa[q], false);
                f32x2 h0 = __builtin_amdgcn_cvt_pk_f32_fp8(wa[q], true);
                f32x2 l1 = __builtin_amdgcn_cvt_pk_f32_fp8(wb[q], false);
                f32x2 h1 = __builtin_amdgcn_cvt_pk_f32_fp8(wb[q], true);
                f32x2 l2 = __builtin_amdgcn_cvt_pk_f32_fp8(wc[q], false);
                f32x2 h2 = __builtin_amdgcn_cvt_pk_f32_fp8(wc[q], true);
                f32x2 l3 = __builtin_amdgcn_cvt_pk_f32_fp8(wd[q], false);
                f32x2 h3 = __builtin_amdgcn_cvt_pk_f32_fp8(wd[q], true);
                acc[q * 4 + 0] += (l0[0] + l1[0]) + (l2[0] + l3[0]);
                acc[q * 4 + 1] += (l0[1] + l1[1]) + (l2[1] + l3[1]);
                acc[q * 4 + 2] += (h0[0] + h1[0]) + (h2[0] + h3[0]);
                acc[q * 4 + 3] += (h0[1] + h1[1]) + (h2[1] + h3[1]);
            }
        }
        for (; j < e; j += 8) {           // tail
            int c = col[j];
            int4 w = *(const int4*)(X + (size_t)c * 128 + f * 16);
            const int* wa = (const int*)&w;
#pragma unroll
            for (int q = 0; q < 4; ++q) {
                f32x2 l = __builtin_amdgcn_cvt_pk_f32_fp8(wa[q], false);
                f32x2 h = __builtin_amdgcn_cvt_pk_f32_fp8(wa[q], true);
                acc[q * 4 + 0] += l[0];
                acc[q * 4 + 1] += l[1];
                acc[q * 4 + 2] += h[0];
                acc[q * 4 + 3] += h[1];
            }
        }
#pragma unroll
        for (int k = 0; k < 16; ++k) {
            acc[k] += __shfl_xor(acc[k], 8, 64);
            acc[k] += __shfl_xor(acc[k], 16, 64);
            acc[k] += __shfl_xor(acc[k], 32, 64);
        }
        if (g == 0) {
            int deg = e - b;
            float r = 1.0f / (float)(deg > 0 ? deg : 1);
            half8 o0, o1;
#pragma unroll
            for (int k = 0; k < 8; ++k) o0[k] = (_Float16)(acc[k] * r);
#pragma unroll
            for (int k = 0; k < 8; ++k) o1[k] = (_Float16)(acc[8 + k] * r);
            _Float16* op = out + (size_t)nloc * 128 + f * 16;
            *(half8*)op = o0;
            *(half8*)(op + 8) = o1;
        }
    }
}

// ---------------- dispatches 5/7: merged MFMA dual GEMM ------------------------------------------
struct GemmDual {
    const __half *A1d, *A2d, *A1g, *A2g;
    const _Float16 *W1d, *W2d, *W1g, *W2g;
    const float *biasd, *biasg;
    float *Yfd, *Yfg;
    __half *Yhd, *Yhg;
    unsigned char *Y8d, *Y8g;
};
__global__ __launch_bounds__(256) void gemm2(GemmDual p, int nblkD, int layer) {
    int bx = blockIdx.x;
    bool isD = bx < nblkD;
    const __half* A1 = isD ? p.A1d : p.A1g;
    const __half* A2 = isD ? p.A2d : p.A2g;
    const _Float16* W1 = isD ? p.W1d : p.W1g;
    const _Float16* W2 = isD ? p.W2d : p.W2g;
    const float* bias = isD ? p.biasd : p.biasg;
    float* Yf = isD ? p.Yfd : p.Yfg;
    __half* Yh = isD ? p.Yhd : p.Yhg;
    unsigned char* Y8 = isD ? p.Y8d : p.Y8g;
    int n = isD ? ND : NG, b0 = isD ? bx : bx - nblkD;
    int t = threadIdx.x;
    int wave = t >> 6, lane = t & 63;
    int row0 = b0 * 64 + wave * 16;
    if (row0 >= n) return;
    int m = lane & 15, quad = lane >> 4;
    int arow = row0 + m;
    if (arow >= n) arow = n - 1;
    const _Float16* a1p = (const _Float16*)A1 + (size_t)arow * 128 + quad * 8;
    const _Float16* a2p = (const _Float16*)A2 + (size_t)arow * 128 + quad * 8;
    half8 a1[4], a2[4];
#pragma unroll
    for (int kc = 0; kc < 4; ++kc) {
        a1[kc] = *(const half8*)(a1p + kc * 32);
        a2[kc] = *(const half8*)(a2p + kc * 32);
    }
#pragma unroll
    for (int ntile = 0; ntile < 8; ++ntile) {
        f32x4 acc = {0.f, 0.f, 0.f, 0.f};
#pragma unroll
        for (int kc = 0; kc < 4; ++kc) {
            half8 b1 = *(const half8*)(W1 + (size_t)((ntile * 4 + kc) * 64 + lane) * 8);
            acc = __builtin_amdgcn_mfma_f32_16x16x32_f16(a1[kc], b1, acc, 0, 0, 0);
            half8 b2 = *(const half8*)(W2 + (size_t)((ntile * 4 + kc) * 64 + lane) * 8);
            acc = __builtin_amdgcn_mfma_f32_16x16x32_f16(a2[kc], b2, acc, 0, 0, 0);
        }
        int colx = ntile * 16 + m;
        float bb = bias[colx];
#pragma unroll
        for (int r = 0; r < 4; ++r) {
            int rr = row0 + quad * 4 + r;
            if (rr < n) {
                float v = acc[r] + bb;
                if (layer == 2) {
                    Yf[(size_t)rr * 128 + colx] = v;
                } else {
                    Yh[(size_t)rr * 128 + colx] = __float2half(v);
                    int p8 = __builtin_amdgcn_cvt_pk_fp8_f32(v, v, 0, false);
                    Y8[(size_t)rr * 128 + colx] = (unsigned char)(p8 & 0xff);
                }
            }
        }
    }
}

extern "C" void kernel_launch(void* const* d_in, const int* in_sizes, int n_in,
                              void* d_out, int out_size, void* d_ws, size_t ws_size,
                              hipStream_t stream) {
    const float* x_d = (const float*)d_in[0];
    const float* x_g = (const float*)d_in[1];
    const int*   src = (const int*)d_in[2];
    const int*   dst = (const int*)d_in[3];
    float* out = (float*)d_out;

    char* ws = (char*)d_ws;
    unsigned int*   flags = (unsigned int*)(ws + OFF_CNT);
    int*            row   = (int*)(ws + OFF_ROW);
    unsigned short* partD = (unsigned short*)(ws + OFF_PARTD);
    unsigned short* partG = (unsigned short*)(ws + OFF_PARTG);
    unsigned short* col   = (unsigned short*)(ws + OFF_COL);
    _Float16*       wsw   = (_Float16*)(ws + OFF_WSW);
    __half*         xd_h  = (__half*)(ws + OFF_XDH);
    __half*         xg_h  = (__half*)(ws + OFF_XGH);
    unsigned char*  x8d   = (unsigned char*)(ws + OFF_X8D);
    unsigned char*  x8g   = (unsigned char*)(ws + OFF_X8G);
    __half*         md_h  = (__half*)(ws + OFF_MDH);
    __half*         mg_h  = (__half*)(ws + OFF_MGH);
    __half*         d1_h  = (__half*)(ws + OFF_D1H);
    __half*         g1_h  = (__half*)(ws + OFF_G1H);
    unsigned char*  d1_8  = (unsigned char*)(ws + OFF_D18);
    unsigned char*  g1_8  = (unsigned char*)(ws + OFF_G18);

    const int E = in_sizes[2];              // 1,000,000
    const int nblkD = (ND + 63) / 64;       // 391
    const int nblkG = (NG + 63) / 64;       // 313

    WPtrs wp;
    wp.w[0] = (const float*)d_in[4];   // w1_dg_l
    wp.w[1] = (const float*)d_in[6];   // w1_dg_r
    wp.w[2] = (const float*)d_in[7];   // w1_gd_l
    wp.w[3] = (const float*)d_in[9];   // w1_gd_r
    wp.w[4] = (const float*)d_in[10];  // w2_dg_l
    wp.w[5] = (const float*)d_in[12];  // w2_dg_r
    wp.w[6] = (const float*)d_in[13];  // w2_gd_l
    wp.w[7] = (const float*)d_in[15];  // w2_gd_r
    const float* b1_dg = (const float*)d_in[5];
    const float* b1_gd = (const float*)d_in[8];
    const float* b2_dg = (const float*)d_in[11];
    const float* b2_gd = (const float*)d_in[14];

    // 1. hist + prep (independent, disjoint block ranges) + flag zeroing
    prep_hist<<<2 * NBLK + PREPB, 256, 0, stream>>>(x_d, x_g, xd_h, xg_h, x8d, x8g,
                                                    wp, wsw, src, dst, partD, partG, flags, E);
    // 2. fused scan -> rowptr (decoupled lookback, NBLK=64)
    scanall<<<NSB, 256, 0, stream>>>(partD, partG, row, flags, E);
    // 3. XCD-write-local CSR fill
    fill2x<<<NBLK * 8, 256, 0, stream>>>(src, dst, row, partD, partG, col, E);

    // 4-5. layer 1
    agg8m<<<AGGB, 256, 0, stream>>>(x8g, x8d, row, col, md_h, mg_h);
    GemmDual g1p;
    g1p.A1d = md_h; g1p.A2d = xd_h; g1p.W1d = wsw + 2 * 16384; g1p.W2d = wsw + 3 * 16384;
    g1p.biasd = b1_gd; g1p.Yfd = nullptr; g1p.Yhd = d1_h; g1p.Y8d = d1_8;
    g1p.A1g = mg_h; g1p.A2g = xg_h; g1p.W1g = wsw + 0 * 16384; g1p.W2g = wsw + 1 * 16384;
    g1p.biasg = b1_dg; g1p.Yfg = nullptr; g1p.Yhg = g1_h; g1p.Y8g = g1_8;
    gemm2<<<nblkD + nblkG, 256, 0, stream>>>(g1p, nblkD, 1);

    // 6-7. layer 2
    agg8m<<<AGGB, 256, 0, stream>>>(g1_8, d1_8, row, col, md_h, mg_h);
    GemmDual g2p;
    g2p.A1d = md_h; g2p.A2d = d1_h; g2p.W1d = wsw + 6 * 16384; g2p.W2d = wsw + 7 * 16384;
    g2p.biasd = b2_gd; g2p.Yfd = out; g2p.Yhd = nullptr; g2p.Y8d = nullptr;
    g2p.A1g = mg_h; g2p.A2g = g1_h; g2p.W1g = wsw + 4 * 16384; g2p.W2g = wsw + 5 * 16384;
    g2p.biasg = b2_dg; g2p.Yfg = out + (size_t)ND * 128; g2p.Yhg = nullptr; g2p.Y8g = nullptr;
    gemm2<<<nblkD + nblkG, 256, 0, stream>>>(g2p, nblkD, 2);
}

// Round 9
// 263.948 us; speedup vs baseline: 1.5637x; 1.0453x over previous
//
#include <hip/hip_runtime.h>
#include <hip/hip_fp16.h>

#define ND 25000
#define NG 20000
#define NTOT (ND + NG)      // 45000
#define NBLK 64             // hist/fill slices PER NODE TYPE (scan traffic/iters halved vs 128)
#define PREPB 1024          // prep blocks appended after the 2*NBLK hist blocks
#define NSB 176             // scan blocks: ceil(45000/256)
#define DRNG 6250           // disease nodes per XCD range (ND/4)
#define GRNG 5000           // gene nodes per XCD range (NG/4)
#define AGG_SLOTS 1563      // ceil(DRNG/4); agg grid = 8*AGG_SLOTS (oversubscribed 1-wave/node)
#define AGG_GRID (8 * AGG_SLOTS)

typedef _Float16 half8 __attribute__((ext_vector_type(8)));
typedef float f32x4 __attribute__((ext_vector_type(4)));
typedef float f32x2 __attribute__((ext_vector_type(2)));

// ---- workspace layout (bytes), 256B-aligned ----
#define OFF_CNT    0ull           // NSB u32 lookback flags
#define OFF_ROW    180224ull      // NTOT+1 int
#define OFF_PARTD  360704ull      // NBLK*ND u16 (3,200,000)
#define OFF_PARTG  6760704ull     // NBLK*NG u16 (2,560,000)
#define OFF_COL    11880704ull    // 2*NE u16
#define OFF_WSW    15880704ull    // 8*128*128 half
#define OFF_XDH    16142848ull    // ND*128 half
#define OFF_XGH    22542848ull    // NG*128 half
#define OFF_X8D    27662848ull    // ND*128 fp8
#define OFF_X8G    30862848ull    // NG*128 fp8
#define OFF_MDH    33422848ull    // ND*128 half
#define OFF_MGH    39822848ull    // NG*128 half
#define OFF_D1H    44942848ull    // ND*128 half
#define OFF_G1H    51342848ull    // NG*128 half
#define OFF_D18    56462848ull    // ND*128 fp8
#define OFF_G18    59662848ull    // NG*128 fp8  (end ~62.2 MB)

struct WPtrs { const float* w[8]; };

// ---------------- dispatch 1: hist (blocks 0..2*NBLK-1) + prep/convert/swizzle (rest) ------------
__global__ __launch_bounds__(256) void prep_hist(const float* __restrict__ xd,
                                                 const float* __restrict__ xg,
                                                 __half* __restrict__ ydh,
                                                 __half* __restrict__ ygh,
                                                 unsigned char* __restrict__ y8d,
                                                 unsigned char* __restrict__ y8g,
                                                 WPtrs wp, _Float16* __restrict__ wsw,
                                                 const int* __restrict__ src,
                                                 const int* __restrict__ dst,
                                                 unsigned short* __restrict__ partD,
                                                 unsigned short* __restrict__ partG,
                                                 unsigned int* __restrict__ flags, int E) {
    __shared__ unsigned int h[12544];     // 50176 B
    int bx = blockIdx.x, t = threadIdx.x;
    if (bx < 2 * NBLK) {                  // ---- LDS-privatized histogram ----
        bool isD = bx < NBLK;
        int bb = isD ? bx : bx - NBLK;
        const int* key = isD ? src : dst;
        int nw = isD ? (ND / 2) : (NG / 2);
        for (int i = t; i < nw; i += 256) h[i] = 0;
        __syncthreads();
        int e0 = (int)(((long long)E * bb) / NBLK);
        int e1 = (int)(((long long)E * (bb + 1)) / NBLK);
        for (int e = e0 + t; e < e1; e += 256) {
            int k = key[e];
            atomicAdd(&h[k >> 1], 1u << ((k & 1) * 16));
        }
        __syncthreads();
        unsigned int* po = (unsigned int*)((isD ? partD : partG) + (size_t)bb * (isD ? ND : NG));
        for (int i = t; i < nw; i += 256) po[i] = h[i];
        return;
    }
    int pb = bx - 2 * NBLK;               // ---- prep: convert + swizzle ----
    if (pb < 8) {   // W swizzle: slot=(ntile*4+kc)*64+lane; elem j = W[kc*32+(lane>>4)*8+j][ntile*16+(lane&15)]
        const float* W = wp.w[pb];
        _Float16* o = wsw + (size_t)pb * 16384;
        for (int rep = 0; rep < 8; ++rep) {
            int slot = rep * 256 + t;
            int lane = slot & 63, grp = slot >> 6;
            int kc = grp & 3, ntile = grp >> 2;
            int nn = ntile * 16 + (lane & 15);
            int kb = kc * 32 + (lane >> 4) * 8;
            half8 v;
#pragma unroll
            for (int j = 0; j < 8; ++j) v[j] = (_Float16)W[(size_t)(kb + j) * 128 + nn];
            *(half8*)(o + (size_t)slot * 8) = v;
        }
    } else if (pb == 8 && t < NSB) {      // zero lookback flags for scanall
        flags[t] = 0u;
    }
    const int ndq = ND * 32;
    const int tot = ndq + NG * 32;
    for (int i = pb * 256 + t; i < tot; i += PREPB * 256) {
        const float* x;
        __half* y;
        unsigned char* y8;
        int idx;
        if (i < ndq) { x = xd; y = ydh; y8 = y8d; idx = i; }
        else         { x = xg; y = ygh; y8 = y8g; idx = i - ndq; }
        float4 v = ((const float4*)x)[idx];
        ((__half2*)y)[idx * 2 + 0] = __floats2half2_rn(v.x, v.y);
        ((__half2*)y)[idx * 2 + 1] = __floats2half2_rn(v.z, v.w);
        int p8 = __builtin_amdgcn_cvt_pk_fp8_f32(v.x, v.y, 0, false);
        p8 = __builtin_amdgcn_cvt_pk_fp8_f32(v.z, v.w, p8, true);
        ((int*)y8)[idx] = p8;
    }
}

// ---------------- dispatch 2: fused column-scan + row-ptr scan (decoupled lookback) --------------
// NBLK=64: per-key loop and partial traffic halved vs the 253us round-5 config.
__global__ __launch_bounds__(256) void scanall(unsigned short* __restrict__ partD,
                                               unsigned short* __restrict__ partG,
                                               int* __restrict__ row,
                                               unsigned int* __restrict__ flags, int E) {
    __shared__ int sd[256];
    __shared__ int sbase;
    int t = threadIdx.x, bid = blockIdx.x;
    int k = bid * 256 + t;
    int run = 0;
    if (k < NTOT) {                       // per-key scan over NBLK partial slices
        unsigned short* part;
        int nb, kk;
        if (k < ND) { part = partD; nb = ND; kk = k; }
        else        { part = partG; nb = NG; kk = k - ND; }
#pragma unroll 8
        for (int b = 0; b < NBLK; ++b) {
            size_t idx = (size_t)b * nb + kk;
            int v = part[idx];
            part[idx] = (unsigned short)run;
            run += v;
        }
    }
    int tsum = run;                       // this key's total degree
    sd[t] = tsum;
    __syncthreads();
    for (int off = 1; off < 256; off <<= 1) {   // block inclusive scan
        int x = (t >= off) ? sd[t - off] : 0;
        __syncthreads();
        sd[t] += x;
        __syncthreads();
    }
    if (t == 0) {                         // publish block aggregate (+1 so 0 == not-ready)
        unsigned int agg = (unsigned int)sd[255] + 1u;
        __hip_atomic_store(&flags[bid], agg, __ATOMIC_RELEASE, __HIP_MEMORY_SCOPE_AGENT);
    }
    if (t < 64) {                         // parallel lookback: sum ALL predecessor aggregates
        int s = 0;
        for (int i = t; i < bid; i += 64) {
            unsigned int v;
            do {
                v = __hip_atomic_load(&flags[i], __ATOMIC_ACQUIRE, __HIP_MEMORY_SCOPE_AGENT);
            } while (v == 0u);
            s += (int)v - 1;
        }
#pragma unroll
        for (int off = 1; off < 64; off <<= 1) s += __shfl_xor(s, off, 64);
        if (t == 0) sbase = s;
    }
    __syncthreads();
    int base = sbase;
    if (k < NTOT) row[k] = base + sd[t] - tsum;   // global exclusive prefix
    if (bid == 0 && t == 0) row[NTOT] = 2 * E;    // total is static
}

// ---------------- dispatch 3: XCD-write-local CSR fill (NBLK=64 -> 512 blocks) -------------------
__global__ __launch_bounds__(256) void fill2x(const int* __restrict__ src,
                                              const int* __restrict__ dst,
                                              const int* __restrict__ row,
                                              const unsigned short* __restrict__ partD,
                                              const unsigned short* __restrict__ partG,
                                              unsigned short* __restrict__ col, int E) {
    __shared__ unsigned int cur[DRNG];    // 25000 B (max of DRNG, GRNG)
    int t = threadIdx.x, bid = blockIdx.x;
    int x = bid & 7;                      // range / XCD id
    int s = bid >> 3;                     // edge slice 0..NBLK-1
    bool isD = x < 4;
    int r0, rng, nbase, nb;
    const int *key, *val;
    const unsigned short* part;
    if (isD) { r0 = x * DRNG;       rng = DRNG; key = src; val = dst; part = partD; nb = ND; nbase = 0;  }
    else     { r0 = (x - 4) * GRNG; rng = GRNG; key = dst; val = src; part = partG; nb = NG; nbase = ND; }
    for (int i = t; i < rng; i += 256)
        cur[i] = (unsigned int)row[nbase + r0 + i] + part[(size_t)s * nb + r0 + i];
    __syncthreads();
    int e0 = (int)(((long long)E * s) / NBLK);
    int e1 = (int)(((long long)E * (s + 1)) / NBLK);
    for (int e = e0 + t; e < e1; e += 256) {
        int k = key[e];
        if (k >= r0 && k < r0 + rng) {
            unsigned int p = atomicAdd(&cur[k - r0], 1u);
            col[p] = (unsigned short)val[e];
        }
    }
}

// ---------------- dispatches 4/6: fp8 mean aggregation, range-aligned XCD pinning ----------------
// 1 wave per node, OVERSUBSCRIBED grid (12504 blocks) -> hardware block scheduler load-balances
// degree variance (round 8 proved resident grid-stride costs +17us/dispatch). 4 rows in flight.
__global__ __launch_bounds__(256, 8) void agg8m(const unsigned char* __restrict__ Xg,
                                                const unsigned char* __restrict__ Xd,
                                                const int* __restrict__ row,
                                                const unsigned short* __restrict__ col,
                                                __half* __restrict__ outd,
                                                __half* __restrict__ outg) {
    int wid = threadIdx.x >> 6, lane = threadIdx.x & 63;
    int bid = blockIdx.x;
    int xcd = bid & 7, slot = bid >> 3;
    const unsigned char* X;
    _Float16* out;
    int node, nloc;
    if (xcd < 4) {                        // disease range on XCD xcd
        int loc = slot * 4 + wid;
        if (loc >= DRNG) return;
        nloc = xcd * DRNG + loc;
        if (nloc >= ND) return;
        node = nloc;
        X = Xg; out = (_Float16*)outd;
    } else {                              // gene range on XCD xcd
        int loc = slot * 4 + wid;
        if (loc >= GRNG) return;
        nloc = (xcd - 4) * GRNG + loc;
        if (nloc >= NG) return;
        node = ND + nloc;
        X = Xd; out = (_Float16*)outg;
    }
    int b = row[node], e = row[node + 1];
    int g = lane >> 3, f = lane & 7;
    float acc[16];
#pragma unroll
    for (int k = 0; k < 16; ++k) acc[k] = 0.f;
    int j = b + g;
    for (; j + 24 < e; j += 32) {         // 4-deep: all col loads, then all gathers
        int c0 = col[j], c1 = col[j + 8], c2 = col[j + 16], c3 = col[j + 24];
        int4 w0 = *(const int4*)(X + (size_t)c0 * 128 + f * 16);
        int4 w1 = *(const int4*)(X + (size_t)c1 * 128 + f * 16);
        int4 w2 = *(const int4*)(X + (size_t)c2 * 128 + f * 16);
        int4 w3 = *(const int4*)(X + (size_t)c3 * 128 + f * 16);
        const int* wa = (const int*)&w0;
        const int* wb = (const int*)&w1;
        const int* wc = (const int*)&w2;
        const int* wd = (const int*)&w3;
#pragma unroll
        for (int q = 0; q < 4; ++q) {
            f32x2 l0 = __builtin_amdgcn_cvt_pk_f32_fp8(wa[q], false);
            f32x2 h0 = __builtin_amdgcn_cvt_pk_f32_fp8(wa[q], true);
            f32x2 l1 = __builtin_amdgcn_cvt_pk_f32_fp8(wb[q], false);
            f32x2 h1 = __builtin_amdgcn_cvt_pk_f32_fp8(wb[q], true);
            f32x2 l2 = __builtin_amdgcn_cvt_pk_f32_fp8(wc[q], false);
            f32x2 h2 = __builtin_amdgcn_cvt_pk_f32_fp8(wc[q], true);
            f32x2 l3 = __builtin_amdgcn_cvt_pk_f32_fp8(wd[q], false);
            f32x2 h3 = __builtin_amdgcn_cvt_pk_f32_fp8(wd[q], true);
            acc[q * 4 + 0] += (l0[0] + l1[0]) + (l2[0] + l3[0]);
            acc[q * 4 + 1] += (l0[1] + l1[1]) + (l2[1] + l3[1]);
            acc[q * 4 + 2] += (h0[0] + h1[0]) + (h2[0] + h3[0]);
            acc[q * 4 + 3] += (h0[1] + h1[1]) + (h2[1] + h3[1]);
        }
    }
    for (; j < e; j += 8) {               // tail
        int c = col[j];
        int4 w = *(const int4*)(X + (size_t)c * 128 + f * 16);
        const int* wa = (const int*)&w;
#pragma unroll
        for (int q = 0; q < 4; ++q) {
            f32x2 l = __builtin_amdgcn_cvt_pk_f32_fp8(wa[q], false);
            f32x2 h = __builtin_amdgcn_cvt_pk_f32_fp8(wa[q], true);
            acc[q * 4 + 0] += l[0];
            acc[q * 4 + 1] += l[1];
            acc[q * 4 + 2] += h[0];
            acc[q * 4 + 3] += h[1];
        }
    }
#pragma unroll
    for (int k = 0; k < 16; ++k) {
        acc[k] += __shfl_xor(acc[k], 8, 64);
        acc[k] += __shfl_xor(acc[k], 16, 64);
        acc[k] += __shfl_xor(acc[k], 32, 64);
    }
    if (g == 0) {
        int deg = e - b;
        float r = 1.0f / (float)(deg > 0 ? deg : 1);
        half8 o0, o1;
#pragma unroll
        for (int k = 0; k < 8; ++k) o0[k] = (_Float16)(acc[k] * r);
#pragma unroll
        for (int k = 0; k < 8; ++k) o1[k] = (_Float16)(acc[8 + k] * r);
        _Float16* op = out + (size_t)nloc * 128 + f * 16;
        *(half8*)op = o0;
        *(half8*)(op + 8) = o1;
    }
}

// ---------------- dispatches 5/7: merged MFMA dual GEMM ------------------------------------------
struct GemmDual {
    const __half *A1d, *A2d, *A1g, *A2g;
    const _Float16 *W1d, *W2d, *W1g, *W2g;
    const float *biasd, *biasg;
    float *Yfd, *Yfg;
    __half *Yhd, *Yhg;
    unsigned char *Y8d, *Y8g;
};
__global__ __launch_bounds__(256) void gemm2(GemmDual p, int nblkD, int layer) {
    int bx = blockIdx.x;
    bool isD = bx < nblkD;
    const __half* A1 = isD ? p.A1d : p.A1g;
    const __half* A2 = isD ? p.A2d : p.A2g;
    const _Float16* W1 = isD ? p.W1d : p.W1g;
    const _Float16* W2 = isD ? p.W2d : p.W2g;
    const float* bias = isD ? p.biasd : p.biasg;
    float* Yf = isD ? p.Yfd : p.Yfg;
    __half* Yh = isD ? p.Yhd : p.Yhg;
    unsigned char* Y8 = isD ? p.Y8d : p.Y8g;
    int n = isD ? ND : NG, b0 = isD ? bx : bx - nblkD;
    int t = threadIdx.x;
    int wave = t >> 6, lane = t & 63;
    int row0 = b0 * 64 + wave * 16;
    if (row0 >= n) return;
    int m = lane & 15, quad = lane >> 4;
    int arow = row0 + m;
    if (arow >= n) arow = n - 1;
    const _Float16* a1p = (const _Float16*)A1 + (size_t)arow * 128 + quad * 8;
    const _Float16* a2p = (const _Float16*)A2 + (size_t)arow * 128 + quad * 8;
    half8 a1[4], a2[4];
#pragma unroll
    for (int kc = 0; kc < 4; ++kc) {
        a1[kc] = *(const half8*)(a1p + kc * 32);
        a2[kc] = *(const half8*)(a2p + kc * 32);
    }
#pragma unroll
    for (int ntile = 0; ntile < 8; ++ntile) {
        f32x4 acc = {0.f, 0.f, 0.f, 0.f};
#pragma unroll
        for (int kc = 0; kc < 4; ++kc) {
            half8 b1 = *(const half8*)(W1 + (size_t)((ntile * 4 + kc) * 64 + lane) * 8);
            acc = __builtin_amdgcn_mfma_f32_16x16x32_f16(a1[kc], b1, acc, 0, 0, 0);
            half8 b2 = *(const half8*)(W2 + (size_t)((ntile * 4 + kc) * 64 + lane) * 8);
            acc = __builtin_amdgcn_mfma_f32_16x16x32_f16(a2[kc], b2, acc, 0, 0, 0);
        }
        int colx = ntile * 16 + m;
        float bb = bias[colx];
#pragma unroll
        for (int r = 0; r < 4; ++r) {
            int rr = row0 + quad * 4 + r;
            if (rr < n) {
                float v = acc[r] + bb;
                if (layer == 2) {
                    Yf[(size_t)rr * 128 + colx] = v;
                } else {
                    Yh[(size_t)rr * 128 + colx] = __float2half(v);
                    int p8 = __builtin_amdgcn_cvt_pk_fp8_f32(v, v, 0, false);
                    Y8[(size_t)rr * 128 + colx] = (unsigned char)(p8 & 0xff);
                }
            }
        }
    }
}

extern "C" void kernel_launch(void* const* d_in, const int* in_sizes, int n_in,
                              void* d_out, int out_size, void* d_ws, size_t ws_size,
                              hipStream_t stream) {
    const float* x_d = (const float*)d_in[0];
    const float* x_g = (const float*)d_in[1];
    const int*   src = (const int*)d_in[2];
    const int*   dst = (const int*)d_in[3];
    float* out = (float*)d_out;

    char* ws = (char*)d_ws;
    unsigned int*   flags = (unsigned int*)(ws + OFF_CNT);
    int*            row   = (int*)(ws + OFF_ROW);
    unsigned short* partD = (unsigned short*)(ws + OFF_PARTD);
    unsigned short* partG = (unsigned short*)(ws + OFF_PARTG);
    unsigned short* col   = (unsigned short*)(ws + OFF_COL);
    _Float16*       wsw   = (_Float16*)(ws + OFF_WSW);
    __half*         xd_h  = (__half*)(ws + OFF_XDH);
    __half*         xg_h  = (__half*)(ws + OFF_XGH);
    unsigned char*  x8d   = (unsigned char*)(ws + OFF_X8D);
    unsigned char*  x8g   = (unsigned char*)(ws + OFF_X8G);
    __half*         md_h  = (__half*)(ws + OFF_MDH);
    __half*         mg_h  = (__half*)(ws + OFF_MGH);
    __half*         d1_h  = (__half*)(ws + OFF_D1H);
    __half*         g1_h  = (__half*)(ws + OFF_G1H);
    unsigned char*  d1_8  = (unsigned char*)(ws + OFF_D18);
    unsigned char*  g1_8  = (unsigned char*)(ws + OFF_G18);

    const int E = in_sizes[2];              // 1,000,000
    const int nblkD = (ND + 63) / 64;       // 391
    const int nblkG = (NG + 63) / 64;       // 313

    WPtrs wp;
    wp.w[0] = (const float*)d_in[4];   // w1_dg_l
    wp.w[1] = (const float*)d_in[6];   // w1_dg_r
    wp.w[2] = (const float*)d_in[7];   // w1_gd_l
    wp.w[3] = (const float*)d_in[9];   // w1_gd_r
    wp.w[4] = (const float*)d_in[10];  // w2_dg_l
    wp.w[5] = (const float*)d_in[12];  // w2_dg_r
    wp.w[6] = (const float*)d_in[13];  // w2_gd_l
    wp.w[7] = (const float*)d_in[15];  // w2_gd_r
    const float* b1_dg = (const float*)d_in[5];
    const float* b1_gd = (const float*)d_in[8];
    const float* b2_dg = (const float*)d_in[11];
    const float* b2_gd = (const float*)d_in[14];

    // 1. hist + prep (independent, disjoint block ranges) + flag zeroing
    prep_hist<<<2 * NBLK + PREPB, 256, 0, stream>>>(x_d, x_g, xd_h, xg_h, x8d, x8g,
                                                    wp, wsw, src, dst, partD, partG, flags, E);
    // 2. fused scan -> rowptr (decoupled lookback, NBLK=64)
    scanall<<<NSB, 256, 0, stream>>>(partD, partG, row, flags, E);
    // 3. XCD-write-local CSR fill
    fill2x<<<NBLK * 8, 256, 0, stream>>>(src, dst, row, partD, partG, col, E);

    // 4-5. layer 1
    agg8m<<<AGG_GRID, 256, 0, stream>>>(x8g, x8d, row, col, md_h, mg_h);
    GemmDual g1p;
    g1p.A1d = md_h; g1p.A2d = xd_h; g1p.W1d = wsw + 2 * 16384; g1p.W2d = wsw + 3 * 16384;
    g1p.biasd = b1_gd; g1p.Yfd = nullptr; g1p.Yhd = d1_h; g1p.Y8d = d1_8;
    g1p.A1g = mg_h; g1p.A2g = xg_h; g1p.W1g = wsw + 0 * 16384; g1p.W2g = wsw + 1 * 16384;
    g1p.biasg = b1_dg; g1p.Yfg = nullptr; g1p.Yhg = g1_h; g1p.Y8g = g1_8;
    gemm2<<<nblkD + nblkG, 256, 0, stream>>>(g1p, nblkD, 1);

    // 6-7. layer 2
    agg8m<<<AGG_GRID, 256, 0, stream>>>(g1_8, d1_8, row, col, md_h, mg_h);
    GemmDual g2p;
    g2p.A1d = md_h; g2p.A2d = d1_h; g2p.W1d = wsw + 6 * 16384; g2p.W2d = wsw + 7 * 16384;
    g2p.biasd = b2_gd; g2p.Yfd = out; g2p.Yhd = nullptr; g2p.Y8d = nullptr;
    g2p.A1g = mg_h; g2p.A2g = g1_h; g2p.W1g = wsw + 4 * 16384; g2p.W2g = wsw + 5 * 16384;
    g2p.biasg = b2_dg; g2p.Yfg = out + (size_t)ND * 128; g2p.Yhg = nullptr; g2p.Y8g = nullptr;
    gemm2<<<nblkD + nblkG, 256, 0, stream>>>(g2p, nblkD, 2);
}

// Round 10
// 250.019 us; speedup vs baseline: 1.6508x; 1.0557x over previous
//
#include <hip/hip_runtime.h>
#include <hip/hip_fp16.h>

#define ND 25000
#define NG 20000
#define NTOT (ND + NG)      // 45000
#define NBLK 128            // hist/fill slices PER NODE TYPE (2*NBLK = 256 blocks)
#define PREPB 1024          // prep blocks appended after the 256 hist blocks
#define NSB 176             // scan blocks: ceil(45000/256)
#define AGG_SLOTS 1563      // ceil(ceil(ND/4)/4) = 1563; agg grid = 8*AGG_SLOTS
#define AGG_GRID (8 * AGG_SLOTS)

typedef _Float16 half8 __attribute__((ext_vector_type(8)));
typedef float f32x4 __attribute__((ext_vector_type(4)));
typedef float f32x2 __attribute__((ext_vector_type(2)));

// ---- workspace layout (bytes), 256B-aligned ----
#define OFF_CNT    0ull           // NSB u32 lookback flags
#define OFF_ROW    180224ull      // NTOT+1 int
#define OFF_PARTD  360704ull      // NBLK*ND u16 (6,400,000)
#define OFF_PARTG  6760704ull     // NBLK*NG u16 (5,120,000)
#define OFF_COL    11880704ull    // 2*NE u16 (4,000,000)
#define OFF_WSW    15880704ull    // 8*128*128 half (262,144)
#define OFF_XDH    16142848ull    // ND*128 half (6,400,000)
#define OFF_XGH    22542848ull    // NG*128 half (5,120,000)
#define OFF_X8D    27662848ull    // ND*128 fp8 (3,200,000)
#define OFF_X8G    30862848ull    // NG*128 fp8 (2,560,000)
#define OFF_MDH    33422848ull    // ND*128 half (6,400,000)
#define OFF_MGH    39822848ull    // NG*128 half (5,120,000)
#define OFF_D1H    44942848ull    // ND*128 half (6,400,000)
#define OFF_G1H    51342848ull    // NG*128 half (5,120,000)
#define OFF_D18    56462848ull    // ND*128 fp8 (3,200,000)
#define OFF_G18    59662848ull    // NG*128 fp8 (2,560,000)  (end ~62.2 MB)

struct WPtrs { const float* w[8]; };

// ---------------- dispatch 1: hist (blocks 0..2*NBLK-1) + prep/convert/swizzle (rest) ------------
__global__ __launch_bounds__(256) void prep_hist(const float* __restrict__ xd,
                                                 const float* __restrict__ xg,
                                                 __half* __restrict__ ydh,
                                                 __half* __restrict__ ygh,
                                                 unsigned char* __restrict__ y8d,
                                                 unsigned char* __restrict__ y8g,
                                                 WPtrs wp, _Float16* __restrict__ wsw,
                                                 const int* __restrict__ src,
                                                 const int* __restrict__ dst,
                                                 unsigned short* __restrict__ partD,
                                                 unsigned short* __restrict__ partG,
                                                 unsigned int* __restrict__ flags, int E) {
    __shared__ unsigned int h[12544];     // 50176 B
    int bx = blockIdx.x, t = threadIdx.x;
    if (bx < 2 * NBLK) {                  // ---- LDS-privatized histogram ----
        bool isD = bx < NBLK;
        int bb = isD ? bx : bx - NBLK;
        const int* key = isD ? src : dst;
        int nw = isD ? (ND / 2) : (NG / 2);
        for (int i = t; i < nw; i += 256) h[i] = 0;
        __syncthreads();
        int e0 = (int)(((long long)E * bb) / NBLK);
        int e1 = (int)(((long long)E * (bb + 1)) / NBLK);
        for (int e = e0 + t; e < e1; e += 256) {
            int k = key[e];
            atomicAdd(&h[k >> 1], 1u << ((k & 1) * 16));
        }
        __syncthreads();
        unsigned int* po = (unsigned int*)((isD ? partD : partG) + (size_t)bb * (isD ? ND : NG));
        for (int i = t; i < nw; i += 256) po[i] = h[i];
        return;
    }
    int pb = bx - 2 * NBLK;               // ---- prep: convert + swizzle ----
    if (pb < 8) {   // W swizzle: slot=(ntile*4+kc)*64+lane; elem j = W[kc*32+(lane>>4)*8+j][ntile*16+(lane&15)]
        const float* W = wp.w[pb];
        _Float16* o = wsw + (size_t)pb * 16384;
        for (int rep = 0; rep < 8; ++rep) {
            int slot = rep * 256 + t;
            int lane = slot & 63, grp = slot >> 6;
            int kc = grp & 3, ntile = grp >> 2;
            int nn = ntile * 16 + (lane & 15);
            int kb = kc * 32 + (lane >> 4) * 8;
            half8 v;
#pragma unroll
            for (int j = 0; j < 8; ++j) v[j] = (_Float16)W[(size_t)(kb + j) * 128 + nn];
            *(half8*)(o + (size_t)slot * 8) = v;
        }
    } else if (pb == 8 && t < NSB) {      // zero lookback flags for scanall
        flags[t] = 0u;
    }
    const int ndq = ND * 32;
    const int tot = ndq + NG * 32;
    for (int i = pb * 256 + t; i < tot; i += PREPB * 256) {
        const float* x;
        __half* y;
        unsigned char* y8;
        int idx;
        if (i < ndq) { x = xd; y = ydh; y8 = y8d; idx = i; }
        else         { x = xg; y = ygh; y8 = y8g; idx = i - ndq; }
        float4 v = ((const float4*)x)[idx];
        ((__half2*)y)[idx * 2 + 0] = __floats2half2_rn(v.x, v.y);
        ((__half2*)y)[idx * 2 + 1] = __floats2half2_rn(v.z, v.w);
        int p8 = __builtin_amdgcn_cvt_pk_fp8_f32(v.x, v.y, 0, false);
        p8 = __builtin_amdgcn_cvt_pk_fp8_f32(v.z, v.w, p8, true);
        ((int*)y8)[idx] = p8;
    }
}

// ---------------- dispatch 2: fused column-scan + row-ptr scan (decoupled lookback) --------------
// RELAXED flag atomics (rocPRIM-style): the flag VALUE is the payload; no non-atomic data is
// communicated through it (row/partials cross to the next kernel via the HW boundary flush).
// Acquire polls emit per-poll L2 cache-maintenance on MI355X (R4/R6 lesson: ~25x cost at scale);
// relaxed agent-scope atomics still execute at the coherence point (always fresh) without it.
__global__ __launch_bounds__(256) void scanall(unsigned short* __restrict__ partD,
                                               unsigned short* __restrict__ partG,
                                               int* __restrict__ row,
                                               unsigned int* __restrict__ flags, int E) {
    __shared__ int sd[256];
    __shared__ int sbase;
    int t = threadIdx.x, bid = blockIdx.x;
    int k = bid * 256 + t;
    int run = 0;
    if (k < NTOT) {                       // per-key scan over NBLK partial slices
        unsigned short* part;
        int nb, kk;
        if (k < ND) { part = partD; nb = ND; kk = k; }
        else        { part = partG; nb = NG; kk = k - ND; }
#pragma unroll 8
        for (int b = 0; b < NBLK; ++b) {
            size_t idx = (size_t)b * nb + kk;
            int v = part[idx];
            part[idx] = (unsigned short)run;
            run += v;
        }
    }
    int tsum = run;                       // this key's total degree
    sd[t] = tsum;
    __syncthreads();
    for (int off = 1; off < 256; off <<= 1) {   // block inclusive scan
        int x = (t >= off) ? sd[t - off] : 0;
        __syncthreads();
        sd[t] += x;
        __syncthreads();
    }
    if (t == 0) {                         // publish block aggregate (+1 so 0 == not-ready)
        unsigned int agg = (unsigned int)sd[255] + 1u;
        __hip_atomic_store(&flags[bid], agg, __ATOMIC_RELAXED, __HIP_MEMORY_SCOPE_AGENT);
    }
    if (t < 64) {                         // parallel lookback: sum ALL predecessor aggregates
        int s = 0;
        for (int i = t; i < bid; i += 64) {
            unsigned int v;
            do {
                v = __hip_atomic_load(&flags[i], __ATOMIC_RELAXED, __HIP_MEMORY_SCOPE_AGENT);
            } while (v == 0u);
            s += (int)v - 1;
        }
#pragma unroll
        for (int off = 1; off < 64; off <<= 1) s += __shfl_xor(s, off, 64);
        if (t == 0) sbase = s;
    }
    __syncthreads();
    int base = sbase;
    if (k < NTOT) row[k] = base + sd[t] - tsum;   // global exclusive prefix
    if (bid == 0 && t == 0) row[NTOT] = 2 * E;    // total is static
}

// ---------------- dispatch 3: atomic-free CSR fill -----------------------------------------------
__global__ __launch_bounds__(256) void fill2(const int* __restrict__ src,
                                             const int* __restrict__ dst,
                                             const int* __restrict__ row,
                                             const unsigned short* __restrict__ partD,
                                             const unsigned short* __restrict__ partG,
                                             unsigned short* __restrict__ col, int E) {
    __shared__ unsigned int h[12544];
    int t = threadIdx.x, b = blockIdx.x;
    bool isD = b < NBLK;
    int bb = isD ? b : b - NBLK;
    const int* key = isD ? src : dst;
    const int* val = isD ? dst : src;
    const int* rowp = isD ? row : row + ND;
    int nw = isD ? (ND / 2) : (NG / 2);
    const unsigned int* pi =
        (const unsigned int*)((isD ? partD : partG) + (size_t)bb * (isD ? ND : NG));
    for (int i = t; i < nw; i += 256) h[i] = pi[i];
    __syncthreads();
    int e0 = (int)(((long long)E * bb) / NBLK);
    int e1 = (int)(((long long)E * (bb + 1)) / NBLK);
    for (int e = e0 + t; e < e1; e += 256) {
        int k = key[e];
        int v = val[e];
        unsigned int old = atomicAdd(&h[k >> 1], 1u << ((k & 1) * 16));
        int rank = (old >> ((k & 1) * 16)) & 0xffff;
        col[rowp[k] + rank] = (unsigned short)v;
    }
}

// ---------------- dispatches 4/6: fp8 mean aggregation, XCD-pinned -------------------------------
// 1 wave per node (oversubscribed 12504-block grid: HW scheduler load-balances degree variance).
// Block->XCD mapping (bid&7): XCDs 0-3 aggregate DISEASE nodes (gather table Xg, 2.56 MB),
// XCDs 4-7 aggregate GENE nodes (gather table Xd, 3.2 MB) -> each table stays L2-resident.
__global__ __launch_bounds__(256, 8) void agg8m(const unsigned char* __restrict__ Xg,
                                                const unsigned char* __restrict__ Xd,
                                                const int* __restrict__ row,
                                                const unsigned short* __restrict__ col,
                                                __half* __restrict__ outd,
                                                __half* __restrict__ outg) {
    int wid = threadIdx.x >> 6, lane = threadIdx.x & 63;
    int bid = blockIdx.x;
    int xcd = bid & 7, slot = bid >> 3;
    const unsigned char* X;
    _Float16* out;
    int node, nloc;
    if (xcd < 4) {                        // disease nodes on XCDs 0-3
        int db = slot * 4 + xcd;
        node = db * 4 + wid;
        if (node >= ND) return;
        X = Xg; out = (_Float16*)outd; nloc = node;
    } else {                              // gene nodes on XCDs 4-7
        int gb = slot * 4 + (xcd - 4);
        int gn = gb * 4 + wid;
        if (gn >= NG) return;
        node = ND + gn;
        X = Xd; out = (_Float16*)outg; nloc = gn;
    }
    int b = row[node], e = row[node + 1];
    int g = lane >> 3, f = lane & 7;
    float acc[16];
#pragma unroll
    for (int k = 0; k < 16; ++k) acc[k] = 0.f;
    int j = b + g;
    for (; j + 8 < e; j += 16) {
        int c0 = col[j], c1 = col[j + 8];
        int4 w0 = *(const int4*)(X + (size_t)c0 * 128 + f * 16);
        int4 w1 = *(const int4*)(X + (size_t)c1 * 128 + f * 16);
        const int* wa = (const int*)&w0;
        const int* wb = (const int*)&w1;
#pragma unroll
        for (int q = 0; q < 4; ++q) {
            f32x2 l0 = __builtin_amdgcn_cvt_pk_f32_fp8(wa[q], false);
            f32x2 h0 = __builtin_amdgcn_cvt_pk_f32_fp8(wa[q], true);
            f32x2 l1 = __builtin_amdgcn_cvt_pk_f32_fp8(wb[q], false);
            f32x2 h1 = __builtin_amdgcn_cvt_pk_f32_fp8(wb[q], true);
            acc[q * 4 + 0] += l0[0] + l1[0];
            acc[q * 4 + 1] += l0[1] + l1[1];
            acc[q * 4 + 2] += h0[0] + h1[0];
            acc[q * 4 + 3] += h0[1] + h1[1];
        }
    }
    if (j < e) {
        int c = col[j];
        int4 w = *(const int4*)(X + (size_t)c * 128 + f * 16);
        const int* wa = (const int*)&w;
#pragma unroll
        for (int q = 0; q < 4; ++q) {
            f32x2 l = __builtin_amdgcn_cvt_pk_f32_fp8(wa[q], false);
            f32x2 h = __builtin_amdgcn_cvt_pk_f32_fp8(wa[q], true);
            acc[q * 4 + 0] += l[0];
            acc[q * 4 + 1] += l[1];
            acc[q * 4 + 2] += h[0];
            acc[q * 4 + 3] += h[1];
        }
    }
#pragma unroll
    for (int k = 0; k < 16; ++k) {
        acc[k] += __shfl_xor(acc[k], 8, 64);
        acc[k] += __shfl_xor(acc[k], 16, 64);
        acc[k] += __shfl_xor(acc[k], 32, 64);
    }
    if (g == 0) {
        int deg = e - b;
        float r = 1.0f / (float)(deg > 0 ? deg : 1);
        half8 o0, o1;
#pragma unroll
        for (int k = 0; k < 8; ++k) o0[k] = (_Float16)(acc[k] * r);
#pragma unroll
        for (int k = 0; k < 8; ++k) o1[k] = (_Float16)(acc[8 + k] * r);
        _Float16* op = out + (size_t)nloc * 128 + f * 16;
        *(half8*)op = o0;
        *(half8*)(op + 8) = o1;
    }
}

// ---------------- dispatches 5/7: merged MFMA dual GEMM ------------------------------------------
struct GemmDual {
    const __half *A1d, *A2d, *A1g, *A2g;
    const _Float16 *W1d, *W2d, *W1g, *W2g;
    const float *biasd, *biasg;
    float *Yfd, *Yfg;
    __half *Yhd, *Yhg;
    unsigned char *Y8d, *Y8g;
};
__global__ __launch_bounds__(256) void gemm2(GemmDual p, int nblkD, int layer) {
    int bx = blockIdx.x;
    bool isD = bx < nblkD;
    const __half* A1 = isD ? p.A1d : p.A1g;
    const __half* A2 = isD ? p.A2d : p.A2g;
    const _Float16* W1 = isD ? p.W1d : p.W1g;
    const _Float16* W2 = isD ? p.W2d : p.W2g;
    const float* bias = isD ? p.biasd : p.biasg;
    float* Yf = isD ? p.Yfd : p.Yfg;
    __half* Yh = isD ? p.Yhd : p.Yhg;
    unsigned char* Y8 = isD ? p.Y8d : p.Y8g;
    int n = isD ? ND : NG, b0 = isD ? bx : bx - nblkD;
    int t = threadIdx.x;
    int wave = t >> 6, lane = t & 63;
    int row0 = b0 * 64 + wave * 16;
    if (row0 >= n) return;
    int m = lane & 15, quad = lane >> 4;
    int arow = row0 + m;
    if (arow >= n) arow = n - 1;
    const _Float16* a1p = (const _Float16*)A1 + (size_t)arow * 128 + quad * 8;
    const _Float16* a2p = (const _Float16*)A2 + (size_t)arow * 128 + quad * 8;
    half8 a1[4], a2[4];
#pragma unroll
    for (int kc = 0; kc < 4; ++kc) {
        a1[kc] = *(const half8*)(a1p + kc * 32);
        a2[kc] = *(const half8*)(a2p + kc * 32);
    }
#pragma unroll
    for (int ntile = 0; ntile < 8; ++ntile) {
        f32x4 acc = {0.f, 0.f, 0.f, 0.f};
#pragma unroll
        for (int kc = 0; kc < 4; ++kc) {
            half8 b1 = *(const half8*)(W1 + (size_t)((ntile * 4 + kc) * 64 + lane) * 8);
            acc = __builtin_amdgcn_mfma_f32_16x16x32_f16(a1[kc], b1, acc, 0, 0, 0);
            half8 b2 = *(const half8*)(W2 + (size_t)((ntile * 4 + kc) * 64 + lane) * 8);
            acc = __builtin_amdgcn_mfma_f32_16x16x32_f16(a2[kc], b2, acc, 0, 0, 0);
        }
        int colx = ntile * 16 + m;
        float bb = bias[colx];
#pragma unroll
        for (int r = 0; r < 4; ++r) {
            int rr = row0 + quad * 4 + r;
            if (rr < n) {
                float v = acc[r] + bb;
                if (layer == 2) {
                    Yf[(size_t)rr * 128 + colx] = v;
                } else {
                    Yh[(size_t)rr * 128 + colx] = __float2half(v);
                    int p8 = __builtin_amdgcn_cvt_pk_fp8_f32(v, v, 0, false);
                    Y8[(size_t)rr * 128 + colx] = (unsigned char)(p8 & 0xff);
                }
            }
        }
    }
}

extern "C" void kernel_launch(void* const* d_in, const int* in_sizes, int n_in,
                              void* d_out, int out_size, void* d_ws, size_t ws_size,
                              hipStream_t stream) {
    const float* x_d = (const float*)d_in[0];
    const float* x_g = (const float*)d_in[1];
    const int*   src = (const int*)d_in[2];
    const int*   dst = (const int*)d_in[3];
    float* out = (float*)d_out;

    char* ws = (char*)d_ws;
    unsigned int*   flags = (unsigned int*)(ws + OFF_CNT);
    int*            row   = (int*)(ws + OFF_ROW);
    unsigned short* partD = (unsigned short*)(ws + OFF_PARTD);
    unsigned short* partG = (unsigned short*)(ws + OFF_PARTG);
    unsigned short* col   = (unsigned short*)(ws + OFF_COL);
    _Float16*       wsw   = (_Float16*)(ws + OFF_WSW);
    __half*         xd_h  = (__half*)(ws + OFF_XDH);
    __half*         xg_h  = (__half*)(ws + OFF_XGH);
    unsigned char*  x8d   = (unsigned char*)(ws + OFF_X8D);
    unsigned char*  x8g   = (unsigned char*)(ws + OFF_X8G);
    __half*         md_h  = (__half*)(ws + OFF_MDH);
    __half*         mg_h  = (__half*)(ws + OFF_MGH);
    __half*         d1_h  = (__half*)(ws + OFF_D1H);
    __half*         g1_h  = (__half*)(ws + OFF_G1H);
    unsigned char*  d1_8  = (unsigned char*)(ws + OFF_D18);
    unsigned char*  g1_8  = (unsigned char*)(ws + OFF_G18);

    const int E = in_sizes[2];              // 1,000,000
    const int nblkD = (ND + 63) / 64;       // 391
    const int nblkG = (NG + 63) / 64;       // 313

    WPtrs wp;
    wp.w[0] = (const float*)d_in[4];   // w1_dg_l
    wp.w[1] = (const float*)d_in[6];   // w1_dg_r
    wp.w[2] = (const float*)d_in[7];   // w1_gd_l
    wp.w[3] = (const float*)d_in[9];   // w1_gd_r
    wp.w[4] = (const float*)d_in[10];  // w2_dg_l
    wp.w[5] = (const float*)d_in[12];  // w2_dg_r
    wp.w[6] = (const float*)d_in[13];  // w2_gd_l
    wp.w[7] = (const float*)d_in[15];  // w2_gd_r
    const float* b1_dg = (const float*)d_in[5];
    const float* b1_gd = (const float*)d_in[8];
    const float* b2_dg = (const float*)d_in[11];
    const float* b2_gd = (const float*)d_in[14];

    // 1. hist + prep (independent, disjoint block ranges) + flag zeroing
    prep_hist<<<2 * NBLK + PREPB, 256, 0, stream>>>(x_d, x_g, xd_h, xg_h, x8d, x8g,
                                                    wp, wsw, src, dst, partD, partG, flags, E);
    // 2. fused scan -> rowptr (decoupled lookback, relaxed atomics)
    scanall<<<NSB, 256, 0, stream>>>(partD, partG, row, flags, E);
    // 3. CSR fill
    fill2<<<2 * NBLK, 256, 0, stream>>>(src, dst, row, partD, partG, col, E);

    // 4-5. layer 1
    agg8m<<<AGG_GRID, 256, 0, stream>>>(x8g, x8d, row, col, md_h, mg_h);
    GemmDual g1p;
    g1p.A1d = md_h; g1p.A2d = xd_h; g1p.W1d = wsw + 2 * 16384; g1p.W2d = wsw + 3 * 16384;
    g1p.biasd = b1_gd; g1p.Yfd = nullptr; g1p.Yhd = d1_h; g1p.Y8d = d1_8;
    g1p.A1g = mg_h; g1p.A2g = xg_h; g1p.W1g = wsw + 0 * 16384; g1p.W2g = wsw + 1 * 16384;
    g1p.biasg = b1_dg; g1p.Yfg = nullptr; g1p.Yhg = g1_h; g1p.Y8g = g1_8;
    gemm2<<<nblkD + nblkG, 256, 0, stream>>>(g1p, nblkD, 1);

    // 6-7. layer 2
    agg8m<<<AGG_GRID, 256, 0, stream>>>(g1_8, d1_8, row, col, md_h, mg_h);
    GemmDual g2p;
    g2p.A1d = md_h; g2p.A2d = d1_h; g2p.W1d = wsw + 6 * 16384; g2p.W2d = wsw + 7 * 16384;
    g2p.biasd = b2_gd; g2p.Yfd = out; g2p.Yhd = nullptr; g2p.Y8d = nullptr;
    g2p.A1g = mg_h; g2p.A2g = g1_h; g2p.W1g = wsw + 4 * 16384; g2p.W2g = wsw + 5 * 16384;
    g2p.biasg = b2_dg; g2p.Yfg = out + (size_t)ND * 128; g2p.Yhg = nullptr; g2p.Y8g = nullptr;
    gemm2<<<nblkD + nblkG, 256, 0, stream>>>(g2p, nblkD, 2);
}